// Round 1
// baseline (4179.149 us; speedup 1.0000x reference)
//
#include <hip/hip_runtime.h>

constexpr int NUc   = 100000;
constexpr int NIc   = 100000;
constexpr int Ec    = 500000;
constexpr int DINc  = 128;
constexpr int DHc   = 256;
constexpr int DOUTc = 128;

// -------------------- degree (in-degree per dst) --------------------
__global__ void deg_kernel(const int* __restrict__ e1_dst, const int* __restrict__ e2_dst,
                           float* __restrict__ deg_item, float* __restrict__ deg_user) {
  int i = blockIdx.x * blockDim.x + threadIdx.x;
  const int stride = gridDim.x * blockDim.x;
  for (; i < 2 * Ec; i += stride) {
    if (i < Ec) atomicAdd(&deg_item[e1_dst[i]], 1.0f);
    else        atomicAdd(&deg_user[e2_dst[i - Ec]], 1.0f);
  }
}

// -------------------- edge scatter-add (segment sum) --------------------
template<int D>
__global__ void scatter_add_kernel(const float* __restrict__ feat,
                                   const int* __restrict__ esrc,
                                   const int* __restrict__ edst,
                                   float* __restrict__ ssum) {
  constexpr int C = D / 4;           // float4 chunks per row
  const int total = Ec * C;          // <= 16M, fits int
  int i = blockIdx.x * blockDim.x + threadIdx.x;
  const int stride = gridDim.x * blockDim.x;
  for (; i < total; i += stride) {
    int e = i / C;
    int c = i - e * C;
    int s = esrc[e];
    int d = edst[e];
    float4 v = *reinterpret_cast<const float4*>(feat + (size_t)s * D + (size_t)c * 4);
    float* p = ssum + (size_t)d * D + (size_t)c * 4;
    atomicAdd(p + 0, v.x);
    atomicAdd(p + 1, v.y);
    atomicAdd(p + 2, v.z);
    atomicAdd(p + 3, v.w);
  }
}

// -------------------- fused SAGE GEMM --------------------
// MODE 0: out = X@Wself + (S*rdeg)@Wneigh + bias   (optional leaky)
// MODE 1: out = X@Wself                            (projection, no bias)
// MODE 2: out = X@Wself + bias + S[row,col]*rdeg[row]  (S pre-projected, width DO)
template<int DI, int DO, int MODE, bool LEAKY>
__global__ __launch_bounds__(256) void sage_gemm(
    const float* __restrict__ X,
    const float* __restrict__ S,
    const float* __restrict__ deg,
    const float* __restrict__ Wself,
    const float* __restrict__ Wneigh,
    const float* __restrict__ bias,
    float* __restrict__ out,
    int N)
{
  constexpr int BM = 64, BN = 64, BK = 32;
  __shared__ float sA[BK][BM + 4];   // k-major (transposed) for float4 frag reads
  __shared__ float sB[BK][BN];
  __shared__ float sRdeg[BM];

  const int tid = threadIdx.x;
  const int gr0 = blockIdx.x * BM;
  const int gc0 = blockIdx.y * BN;

  if (MODE != 1 && tid < BM) {
    int r = gr0 + tid;
    float dg = (r < N) ? deg[r] : 1.0f;
    sRdeg[tid] = 1.0f / fmaxf(dg, 1.0f);
  }
  __syncthreads();

  const int tx  = tid & 15;   // output col group
  const int ty  = tid >> 4;   // output row group
  const int lr  = tid >> 3;   // A-tile row 0..31
  const int lc4 = tid & 7;    // A-tile k-chunk 0..7
  const int kr  = tid >> 4;   // B-tile k row 0..15
  const int kc4 = tid & 15;   // B-tile col chunk 0..15

  float acc[4][4] = {};

  const int npass = (MODE == 0) ? 2 : 1;
  for (int pass = 0; pass < npass; ++pass) {
    const float* A = (pass == 0) ? X : S;
    const float* W = (pass == 0) ? Wself : Wneigh;
    for (int kt = 0; kt < DI; kt += BK) {
      #pragma unroll
      for (int h = 0; h < 2; ++h) {
        int row = lr + 32 * h;
        int grow = gr0 + row;
        grow = grow < N ? grow : N - 1;   // clamp; stores are guarded
        float4 v = *reinterpret_cast<const float4*>(A + (size_t)grow * DI + kt + lc4 * 4);
        if (MODE == 0 && pass == 1) {
          float rs = sRdeg[row];
          v.x *= rs; v.y *= rs; v.z *= rs; v.w *= rs;
        }
        sA[lc4 * 4 + 0][row] = v.x;
        sA[lc4 * 4 + 1][row] = v.y;
        sA[lc4 * 4 + 2][row] = v.z;
        sA[lc4 * 4 + 3][row] = v.w;
      }
      #pragma unroll
      for (int h = 0; h < 2; ++h) {
        int k = kr + 16 * h;
        *reinterpret_cast<float4*>(&sB[k][kc4 * 4]) =
            *reinterpret_cast<const float4*>(W + (size_t)(kt + k) * DO + gc0 + kc4 * 4);
      }
      __syncthreads();
      #pragma unroll
      for (int kk = 0; kk < BK; ++kk) {
        float4 a4 = *reinterpret_cast<const float4*>(&sA[kk][ty * 4]);
        float4 b4 = *reinterpret_cast<const float4*>(&sB[kk][tx * 4]);
        float av[4] = {a4.x, a4.y, a4.z, a4.w};
        float bv[4] = {b4.x, b4.y, b4.z, b4.w};
        #pragma unroll
        for (int i = 0; i < 4; ++i)
          #pragma unroll
          for (int j = 0; j < 4; ++j)
            acc[i][j] = fmaf(av[i], bv[j], acc[i][j]);
      }
      __syncthreads();
    }
  }

  float bv[4] = {0.f, 0.f, 0.f, 0.f};
  if (MODE != 1) {
    #pragma unroll
    for (int j = 0; j < 4; ++j) bv[j] = bias[gc0 + tx * 4 + j];
  }
  #pragma unroll
  for (int i = 0; i < 4; ++i) {
    int row = gr0 + ty * 4 + i;
    if (row < N) {
      float o[4];
      #pragma unroll
      for (int j = 0; j < 4; ++j) o[j] = acc[i][j] + bv[j];
      if (MODE == 2) {
        float rs = sRdeg[ty * 4 + i];
        float4 m4 = *reinterpret_cast<const float4*>(S + (size_t)row * DO + gc0 + tx * 4);
        o[0] += m4.x * rs; o[1] += m4.y * rs; o[2] += m4.z * rs; o[3] += m4.w * rs;
      }
      if (LEAKY) {
        #pragma unroll
        for (int j = 0; j < 4; ++j) o[j] = (o[j] >= 0.f) ? o[j] : 0.01f * o[j];
      }
      *reinterpret_cast<float4*>(out + (size_t)row * DO + gc0 + tx * 4) =
          make_float4(o[0], o[1], o[2], o[3]);
    }
  }
}

extern "C" void kernel_launch(void* const* d_in, const int* in_sizes, int n_in,
                              void* d_out, int out_size, void* d_ws, size_t ws_size,
                              hipStream_t stream) {
  const float* emb_user    = (const float*)d_in[0];
  const float* emb_item    = (const float*)d_in[1];
  const float* W1_self_ui  = (const float*)d_in[2];
  const float* W1_neigh_ui = (const float*)d_in[3];
  const float* b1_ui       = (const float*)d_in[4];
  const float* W1_self_iu  = (const float*)d_in[5];
  const float* W1_neigh_iu = (const float*)d_in[6];
  const float* b1_iu       = (const float*)d_in[7];
  const float* W2_self_ui  = (const float*)d_in[8];
  const float* W2_neigh_ui = (const float*)d_in[9];
  const float* b2_ui       = (const float*)d_in[10];
  const float* W2_self_iu  = (const float*)d_in[11];
  const float* W2_neigh_iu = (const float*)d_in[12];
  const float* b2_iu       = (const float*)d_in[13];
  const int* e1_src = (const int*)d_in[14];
  const int* e1_dst = (const int*)d_in[15];
  const int* e2_src = (const int*)d_in[16];
  const int* e2_dst = (const int*)d_in[17];

  float* ws       = (float*)d_ws;
  float* h1_item  = ws;                                   // NI*256
  float* h1_user  = h1_item + (size_t)NIc * DHc;          // NU*256
  float* agg      = h1_user + (size_t)NUc * DHc;          // 100000*128
  float* pbuf     = agg + (size_t)100000 * 128;           // 100000*128
  float* deg_item = pbuf + (size_t)100000 * 128;          // NI
  float* deg_user = deg_item + NIc;                       // NU

  float* h2_user = (float*)d_out;
  float* h2_item = h2_user + (size_t)NUc * DOUTc;

  dim3 blk(256);
  dim3 g256(1563, 4);   // 100000/64 rows x 256/64 cols
  dim3 g128(1563, 2);   // 100000/64 rows x 128/64 cols

  hipMemsetAsync(deg_item, 0, sizeof(float) * (size_t)(NIc + NUc), stream);
  deg_kernel<<<1024, blk, 0, stream>>>(e1_dst, e2_dst, deg_item, deg_user);

  // ---- layer 1: items receive from users via e1 ----
  hipMemsetAsync(agg, 0, sizeof(float) * (size_t)NIc * DINc, stream);
  scatter_add_kernel<DINc><<<4096, blk, 0, stream>>>(emb_user, e1_src, e1_dst, agg);
  sage_gemm<DINc, DHc, 0, true><<<g256, blk, 0, stream>>>(
      emb_item, agg, deg_item, W1_self_ui, W1_neigh_ui, b1_ui, h1_item, NIc);

  // ---- layer 1: users receive from items via e2 ----
  hipMemsetAsync(agg, 0, sizeof(float) * (size_t)NUc * DINc, stream);
  scatter_add_kernel<DINc><<<4096, blk, 0, stream>>>(emb_item, e2_src, e2_dst, agg);
  sage_gemm<DINc, DHc, 0, true><<<g256, blk, 0, stream>>>(
      emb_user, agg, deg_user, W1_self_iu, W1_neigh_iu, b1_iu, h1_user, NUc);

  // ---- layer 2: items.  project h1_user by W2_neigh_ui (256->128), then aggregate ----
  sage_gemm<DHc, DOUTc, 1, false><<<g128, blk, 0, stream>>>(
      h1_user, nullptr, nullptr, W2_neigh_ui, nullptr, nullptr, pbuf, NUc);
  hipMemsetAsync(agg, 0, sizeof(float) * (size_t)NIc * DOUTc, stream);
  scatter_add_kernel<DOUTc><<<4096, blk, 0, stream>>>(pbuf, e1_src, e1_dst, agg);
  sage_gemm<DHc, DOUTc, 2, false><<<g128, blk, 0, stream>>>(
      h1_item, agg, deg_item, W2_self_ui, nullptr, b2_ui, h2_item, NIc);

  // ---- layer 2: users ----
  sage_gemm<DHc, DOUTc, 1, false><<<g128, blk, 0, stream>>>(
      h1_item, nullptr, nullptr, W2_neigh_iu, nullptr, nullptr, pbuf, NIc);
  hipMemsetAsync(agg, 0, sizeof(float) * (size_t)NUc * DOUTc, stream);
  scatter_add_kernel<DOUTc><<<4096, blk, 0, stream>>>(pbuf, e2_src, e2_dst, agg);
  sage_gemm<DHc, DOUTc, 2, false><<<g128, blk, 0, stream>>>(
      h1_user, agg, deg_user, W2_self_iu, nullptr, b2_iu, h2_user, NUc);
}

// Round 2
// 1131.015 us; speedup vs baseline: 3.6950x; 3.6950x over previous
//
#include <hip/hip_runtime.h>

constexpr int NUc   = 100000;
constexpr int NIc   = 100000;
constexpr int Ec    = 500000;
constexpr int DINc  = 128;
constexpr int DHc   = 256;
constexpr int DOUTc = 128;
constexpr int NB    = (100000 + 255) / 256;   // 391 scan blocks

// -------------------- CSR build --------------------
__global__ void hist_kernel(const int* __restrict__ e1_dst, const int* __restrict__ e2_dst,
                            int* __restrict__ ideg1, int* __restrict__ ideg2) {
  int i = blockIdx.x * blockDim.x + threadIdx.x;
  const int stride = gridDim.x * blockDim.x;
  for (; i < 2 * Ec; i += stride) {
    if (i < Ec) atomicAdd(&ideg1[e1_dst[i]], 1);
    else        atomicAdd(&ideg2[e2_dst[i - Ec]], 1);
  }
}

__global__ void block_reduce_kernel(const int* __restrict__ deg, int* __restrict__ bsum, int n) {
  __shared__ int s[256];
  int t = threadIdx.x, i = blockIdx.x * 256 + t;
  s[t] = (i < n) ? deg[i] : 0;
  __syncthreads();
  for (int st = 128; st > 0; st >>= 1) { if (t < st) s[t] += s[t + st]; __syncthreads(); }
  if (t == 0) bsum[blockIdx.x] = s[0];
}

__global__ void scan_bsums_kernel(const int* __restrict__ bsum, int* __restrict__ bscan, int nb) {
  __shared__ int s[512];
  int t = threadIdx.x;
  int v0 = (t < nb) ? bsum[t] : 0;
  s[t] = v0;
  __syncthreads();
  for (int d = 1; d < 512; d <<= 1) {
    int v = (t >= d) ? s[t - d] : 0;
    __syncthreads();
    s[t] += v;
    __syncthreads();
  }
  if (t < nb) bscan[t] = s[t] - v0;   // exclusive
}

__global__ void scan_blocks_kernel(const int* __restrict__ deg, const int* __restrict__ bscan,
                                   int* __restrict__ off, int n) {
  __shared__ int s[256];
  int t = threadIdx.x, i = blockIdx.x * 256 + t;
  int d = (i < n) ? deg[i] : 0;
  s[t] = d;
  __syncthreads();
  for (int st = 1; st < 256; st <<= 1) {
    int v = (t >= st) ? s[t - st] : 0;
    __syncthreads();
    s[t] += v;
    __syncthreads();
  }
  if (i < n) off[i] = bscan[blockIdx.x] + s[t] - d;
  if (i == 0) off[n] = Ec;   // every dst is in [0,n)
}

__global__ void finalize_csr_kernel(const int* __restrict__ off, int* __restrict__ cur,
                                    float* __restrict__ degf, int n) {
  int i = blockIdx.x * blockDim.x + threadIdx.x;
  if (i < n) {
    int o = off[i];
    cur[i] = o;
    degf[i] = (float)(off[i + 1] - o);
  }
}

__global__ void fill_csr_kernel(const int* __restrict__ e1_src, const int* __restrict__ e1_dst,
                                const int* __restrict__ e2_src, const int* __restrict__ e2_dst,
                                int* __restrict__ cur1, int* __restrict__ csr1,
                                int* __restrict__ cur2, int* __restrict__ csr2) {
  int i = blockIdx.x * blockDim.x + threadIdx.x;
  const int stride = gridDim.x * blockDim.x;
  for (; i < 2 * Ec; i += stride) {
    if (i < Ec) { int p = atomicAdd(&cur1[e1_dst[i]], 1); csr1[p] = e1_src[i]; }
    else        { int e = i - Ec; int p = atomicAdd(&cur2[e2_dst[e]], 1); csr2[p] = e2_src[e]; }
  }
}

// -------------------- gather aggregation (one wave per dst row) --------------------
template<int D>
__global__ __launch_bounds__(256) void gather_sum_kernel(const float* __restrict__ feat,
                                                         const int* __restrict__ off,
                                                         const int* __restrict__ csr,
                                                         float* __restrict__ out, int n) {
  const int wid  = (blockIdx.x * blockDim.x + threadIdx.x) >> 6;  // one wave per dst row
  const int lane = threadIdx.x & 63;
  if (wid >= n) return;
  const int j0 = off[wid], j1 = off[wid + 1];
  const int col = lane * 2;
  float2 acc = make_float2(0.f, 0.f);
  for (int j = j0; j < j1; ++j) {
    int s = csr[j];
    float2 v = *reinterpret_cast<const float2*>(feat + (size_t)s * D + col);
    acc.x += v.x; acc.y += v.y;
  }
  *reinterpret_cast<float2*>(out + (size_t)wid * D + col) = acc;
}

// -------------------- fused SAGE GEMM --------------------
// MODE 0: out = X@Wself + (S*rdeg)@Wneigh + bias   (optional leaky)
// MODE 1: out = X@Wself                            (projection, no bias)
// MODE 2: out = X@Wself + bias + S[row,col]*rdeg[row]  (S pre-projected, width DO)
template<int DI, int DO, int MODE, bool LEAKY>
__global__ __launch_bounds__(256) void sage_gemm(
    const float* __restrict__ X,
    const float* __restrict__ S,
    const float* __restrict__ deg,
    const float* __restrict__ Wself,
    const float* __restrict__ Wneigh,
    const float* __restrict__ bias,
    float* __restrict__ out,
    int N)
{
  constexpr int BM = 64, BN = 64, BK = 32;
  __shared__ float sA[BK][BM + 4];
  __shared__ float sB[BK][BN];
  __shared__ float sRdeg[BM];

  const int tid = threadIdx.x;
  const int gr0 = blockIdx.x * BM;
  const int gc0 = blockIdx.y * BN;

  if (MODE != 1 && tid < BM) {
    int r = gr0 + tid;
    float dg = (r < N) ? deg[r] : 1.0f;
    sRdeg[tid] = 1.0f / fmaxf(dg, 1.0f);
  }
  __syncthreads();

  const int tx  = tid & 15;
  const int ty  = tid >> 4;
  const int lr  = tid >> 3;
  const int lc4 = tid & 7;
  const int kr  = tid >> 4;
  const int kc4 = tid & 15;

  float acc[4][4] = {};

  const int npass = (MODE == 0) ? 2 : 1;
  for (int pass = 0; pass < npass; ++pass) {
    const float* A = (pass == 0) ? X : S;
    const float* W = (pass == 0) ? Wself : Wneigh;
    for (int kt = 0; kt < DI; kt += BK) {
      #pragma unroll
      for (int h = 0; h < 2; ++h) {
        int row = lr + 32 * h;
        int grow = gr0 + row;
        grow = grow < N ? grow : N - 1;
        float4 v = *reinterpret_cast<const float4*>(A + (size_t)grow * DI + kt + lc4 * 4);
        if (MODE == 0 && pass == 1) {
          float rs = sRdeg[row];
          v.x *= rs; v.y *= rs; v.z *= rs; v.w *= rs;
        }
        sA[lc4 * 4 + 0][row] = v.x;
        sA[lc4 * 4 + 1][row] = v.y;
        sA[lc4 * 4 + 2][row] = v.z;
        sA[lc4 * 4 + 3][row] = v.w;
      }
      #pragma unroll
      for (int h = 0; h < 2; ++h) {
        int k = kr + 16 * h;
        *reinterpret_cast<float4*>(&sB[k][kc4 * 4]) =
            *reinterpret_cast<const float4*>(W + (size_t)(kt + k) * DO + gc0 + kc4 * 4);
      }
      __syncthreads();
      #pragma unroll
      for (int kk = 0; kk < BK; ++kk) {
        float4 a4 = *reinterpret_cast<const float4*>(&sA[kk][ty * 4]);
        float4 b4 = *reinterpret_cast<const float4*>(&sB[kk][tx * 4]);
        float av[4] = {a4.x, a4.y, a4.z, a4.w};
        float bv[4] = {b4.x, b4.y, b4.z, b4.w};
        #pragma unroll
        for (int i = 0; i < 4; ++i)
          #pragma unroll
          for (int j = 0; j < 4; ++j)
            acc[i][j] = fmaf(av[i], bv[j], acc[i][j]);
      }
      __syncthreads();
    }
  }

  float bv[4] = {0.f, 0.f, 0.f, 0.f};
  if (MODE != 1) {
    #pragma unroll
    for (int j = 0; j < 4; ++j) bv[j] = bias[gc0 + tx * 4 + j];
  }
  #pragma unroll
  for (int i = 0; i < 4; ++i) {
    int row = gr0 + ty * 4 + i;
    if (row < N) {
      float o[4];
      #pragma unroll
      for (int j = 0; j < 4; ++j) o[j] = acc[i][j] + bv[j];
      if (MODE == 2) {
        float rs = sRdeg[ty * 4 + i];
        float4 m4 = *reinterpret_cast<const float4*>(S + (size_t)row * DO + gc0 + tx * 4);
        o[0] += m4.x * rs; o[1] += m4.y * rs; o[2] += m4.z * rs; o[3] += m4.w * rs;
      }
      if (LEAKY) {
        #pragma unroll
        for (int j = 0; j < 4; ++j) o[j] = (o[j] >= 0.f) ? o[j] : 0.01f * o[j];
      }
      *reinterpret_cast<float4*>(out + (size_t)row * DO + gc0 + tx * 4) =
          make_float4(o[0], o[1], o[2], o[3]);
    }
  }
}

extern "C" void kernel_launch(void* const* d_in, const int* in_sizes, int n_in,
                              void* d_out, int out_size, void* d_ws, size_t ws_size,
                              hipStream_t stream) {
  const float* emb_user    = (const float*)d_in[0];
  const float* emb_item    = (const float*)d_in[1];
  const float* W1_self_ui  = (const float*)d_in[2];
  const float* W1_neigh_ui = (const float*)d_in[3];
  const float* b1_ui       = (const float*)d_in[4];
  const float* W1_self_iu  = (const float*)d_in[5];
  const float* W1_neigh_iu = (const float*)d_in[6];
  const float* b1_iu       = (const float*)d_in[7];
  const float* W2_self_ui  = (const float*)d_in[8];
  const float* W2_neigh_ui = (const float*)d_in[9];
  const float* b2_ui       = (const float*)d_in[10];
  const float* W2_self_iu  = (const float*)d_in[11];
  const float* W2_neigh_iu = (const float*)d_in[12];
  const float* b2_iu       = (const float*)d_in[13];
  const int* e1_src = (const int*)d_in[14];
  const int* e1_dst = (const int*)d_in[15];
  const int* e2_src = (const int*)d_in[16];
  const int* e2_dst = (const int*)d_in[17];

  // ---- workspace layout ----
  float* ws       = (float*)d_ws;
  float* h1_item  = ws;                                   // NI*256
  float* h1_user  = h1_item + (size_t)NIc * DHc;          // NU*256
  float* agg      = h1_user + (size_t)NUc * DHc;          // 100000*128
  float* pbuf     = agg + (size_t)100000 * 128;           // 100000*128
  float* deg_item = pbuf + (size_t)100000 * 128;          // NI
  float* deg_user = deg_item + NIc;                       // NU
  int*   ip       = (int*)(deg_user + NUc);
  int*   ideg1    = ip;              ip += NIc;
  int*   ideg2    = ip;              ip += NUc;
  int*   off1     = ip;              ip += NIc + 1;
  int*   off2     = ip;              ip += NUc + 1;
  int*   cur1     = ip;              ip += NIc + 1;
  int*   cur2     = ip;              ip += NUc + 1;
  int*   csr1     = ip;              ip += Ec;
  int*   csr2     = ip;              ip += Ec;
  int*   bsum1    = ip;              ip += 512;
  int*   bscan1   = ip;              ip += 512;
  int*   bsum2    = ip;              ip += 512;
  int*   bscan2   = ip;              ip += 512;

  float* h2_user = (float*)d_out;
  float* h2_item = h2_user + (size_t)NUc * DOUTc;

  dim3 blk(256);
  dim3 g256(1563, 4);
  dim3 g128(1563, 2);
  const int gatherBlocks = (100000 + 3) / 4;   // 4 waves (rows) per block

  // ---- CSR build (both edge types) ----
  hipMemsetAsync(ideg1, 0, sizeof(int) * (size_t)(NIc + NUc), stream);
  hist_kernel<<<1024, blk, 0, stream>>>(e1_dst, e2_dst, ideg1, ideg2);

  block_reduce_kernel<<<NB, blk, 0, stream>>>(ideg1, bsum1, NIc);
  scan_bsums_kernel<<<1, 512, 0, stream>>>(bsum1, bscan1, NB);
  scan_blocks_kernel<<<NB, blk, 0, stream>>>(ideg1, bscan1, off1, NIc);
  finalize_csr_kernel<<<NB, blk, 0, stream>>>(off1, cur1, deg_item, NIc);

  block_reduce_kernel<<<NB, blk, 0, stream>>>(ideg2, bsum2, NUc);
  scan_bsums_kernel<<<1, 512, 0, stream>>>(bsum2, bscan2, NB);
  scan_blocks_kernel<<<NB, blk, 0, stream>>>(ideg2, bscan2, off2, NUc);
  finalize_csr_kernel<<<NB, blk, 0, stream>>>(off2, cur2, deg_user, NUc);

  fill_csr_kernel<<<1024, blk, 0, stream>>>(e1_src, e1_dst, e2_src, e2_dst,
                                            cur1, csr1, cur2, csr2);

  // ---- layer 1: items receive from users via e1 ----
  gather_sum_kernel<DINc><<<gatherBlocks, blk, 0, stream>>>(emb_user, off1, csr1, agg, NIc);
  sage_gemm<DINc, DHc, 0, true><<<g256, blk, 0, stream>>>(
      emb_item, agg, deg_item, W1_self_ui, W1_neigh_ui, b1_ui, h1_item, NIc);

  // ---- layer 1: users receive from items via e2 ----
  gather_sum_kernel<DINc><<<gatherBlocks, blk, 0, stream>>>(emb_item, off2, csr2, agg, NUc);
  sage_gemm<DINc, DHc, 0, true><<<g256, blk, 0, stream>>>(
      emb_user, agg, deg_user, W1_self_iu, W1_neigh_iu, b1_iu, h1_user, NUc);

  // ---- layer 2: items.  project h1_user (256->128) then aggregate ----
  sage_gemm<DHc, DOUTc, 1, false><<<g128, blk, 0, stream>>>(
      h1_user, nullptr, nullptr, W2_neigh_ui, nullptr, nullptr, pbuf, NUc);
  gather_sum_kernel<DOUTc><<<gatherBlocks, blk, 0, stream>>>(pbuf, off1, csr1, agg, NIc);
  sage_gemm<DHc, DOUTc, 2, false><<<g128, blk, 0, stream>>>(
      h1_item, agg, deg_item, W2_self_ui, nullptr, b2_ui, h2_item, NIc);

  // ---- layer 2: users ----
  sage_gemm<DHc, DOUTc, 1, false><<<g128, blk, 0, stream>>>(
      h1_item, nullptr, nullptr, W2_neigh_iu, nullptr, nullptr, pbuf, NIc);
  gather_sum_kernel<DOUTc><<<gatherBlocks, blk, 0, stream>>>(pbuf, off2, csr2, agg, NUc);
  sage_gemm<DHc, DOUTc, 2, false><<<g128, blk, 0, stream>>>(
      h1_user, agg, deg_user, W2_self_iu, nullptr, b2_iu, h2_user, NUc);
}

// Round 3
// 574.059 us; speedup vs baseline: 7.2800x; 1.9702x over previous
//
#include <hip/hip_runtime.h>
#include <stdint.h>

typedef unsigned short u16;
typedef unsigned int   u32;
typedef __attribute__((ext_vector_type(8))) short bf16x8;
typedef __attribute__((ext_vector_type(4))) float f32x4;

constexpr int NUc = 100000;
constexpr int NIc = 100000;
constexpr int Ec  = 500000;
constexpr int Mrows = 100000;
constexpr int NB  = (100000 + 255) / 256;   // 391 scan blocks

__device__ __forceinline__ u16 f2bf(float f) {
  u32 u = __float_as_uint(f);
  u += 0x7fffu + ((u >> 16) & 1u);          // round-to-nearest-even
  return (u16)(u >> 16);
}
__device__ __forceinline__ float bf2f(u16 h) { return __uint_as_float(((u32)h) << 16); }

// ==================== CSR build ====================
__global__ void hist_kernel(const int* __restrict__ e1_dst, const int* __restrict__ e2_dst,
                            int* __restrict__ ideg1, int* __restrict__ ideg2) {
  int i = blockIdx.x * blockDim.x + threadIdx.x;
  const int stride = gridDim.x * blockDim.x;
  for (; i < 2 * Ec; i += stride) {
    if (i < Ec) atomicAdd(&ideg1[e1_dst[i]], 1);
    else        atomicAdd(&ideg2[e2_dst[i - Ec]], 1);
  }
}

__global__ void block_reduce_kernel(const int* __restrict__ deg, int* __restrict__ bsum, int n) {
  __shared__ int s[256];
  int t = threadIdx.x, i = blockIdx.x * 256 + t;
  s[t] = (i < n) ? deg[i] : 0;
  __syncthreads();
  for (int st = 128; st > 0; st >>= 1) { if (t < st) s[t] += s[t + st]; __syncthreads(); }
  if (t == 0) bsum[blockIdx.x] = s[0];
}

__global__ void scan_bsums_kernel(const int* __restrict__ bsum, int* __restrict__ bscan, int nb) {
  __shared__ int s[512];
  int t = threadIdx.x;
  int v0 = (t < nb) ? bsum[t] : 0;
  s[t] = v0;
  __syncthreads();
  for (int d = 1; d < 512; d <<= 1) {
    int v = (t >= d) ? s[t - d] : 0;
    __syncthreads();
    s[t] += v;
    __syncthreads();
  }
  if (t < nb) bscan[t] = s[t] - v0;   // exclusive
}

__global__ void scan_blocks_kernel(const int* __restrict__ deg, const int* __restrict__ bscan,
                                   int* __restrict__ off, int n) {
  __shared__ int s[256];
  int t = threadIdx.x, i = blockIdx.x * 256 + t;
  int d = (i < n) ? deg[i] : 0;
  s[t] = d;
  __syncthreads();
  for (int st = 1; st < 256; st <<= 1) {
    int v = (t >= st) ? s[t - st] : 0;
    __syncthreads();
    s[t] += v;
    __syncthreads();
  }
  if (i < n) off[i] = bscan[blockIdx.x] + s[t] - d;
  if (i == 0) off[n] = Ec;
}

__global__ void init_cursor_kernel(const int* __restrict__ off, int* __restrict__ cur, int n) {
  int i = blockIdx.x * blockDim.x + threadIdx.x;
  if (i < n) cur[i] = off[i];
}

__global__ void fill_csr_kernel(const int* __restrict__ e1_src, const int* __restrict__ e1_dst,
                                const int* __restrict__ e2_src, const int* __restrict__ e2_dst,
                                int* __restrict__ cur1, int* __restrict__ csr1,
                                int* __restrict__ cur2, int* __restrict__ csr2) {
  int i = blockIdx.x * blockDim.x + threadIdx.x;
  const int stride = gridDim.x * blockDim.x;
  for (; i < 2 * Ec; i += stride) {
    if (i < Ec) { int p = atomicAdd(&cur1[e1_dst[i]], 1); csr1[p] = e1_src[i]; }
    else        { int e = i - Ec; int p = atomicAdd(&cur2[e2_dst[e]], 1); csr2[p] = e2_src[e]; }
  }
}

// ==================== fp32 -> bf16 cast ====================
__global__ void cast_f32_bf16(const float* __restrict__ in, u16* __restrict__ out, int n4) {
  int i = blockIdx.x * blockDim.x + threadIdx.x;
  const int stride = gridDim.x * blockDim.x;
  for (; i < n4; i += stride) {
    float4 v = reinterpret_cast<const float4*>(in)[i];
    ushort4 o;
    o.x = f2bf(v.x); o.y = f2bf(v.y); o.z = f2bf(v.z); o.w = f2bf(v.w);
    reinterpret_cast<ushort4*>(out)[i] = o;
  }
}

// ==================== weight prep: bf16, transposed [N][K], L1 stacked ====================
__global__ void prep_weights(const float* __restrict__ W1s_ui, const float* __restrict__ W1n_ui,
                             const float* __restrict__ W1s_iu, const float* __restrict__ W1n_iu,
                             const float* __restrict__ W2s_ui, const float* __restrict__ W2n_ui,
                             const float* __restrict__ W2s_iu, const float* __restrict__ W2n_iu,
                             u16* __restrict__ Wt1_ui, u16* __restrict__ Wt1_iu,
                             u16* __restrict__ Wt2s_ui, u16* __restrict__ Wt2n_ui,
                             u16* __restrict__ Wt2s_iu, u16* __restrict__ Wt2n_iu) {
  int i = blockIdx.x * blockDim.x + threadIdx.x;
  if (i < 65536) {                       // Wt1_ui [256][256]
    int n = i >> 8, k = i & 255;
    Wt1_ui[i] = f2bf(k < 128 ? W1s_ui[k * 256 + n] : W1n_ui[(k - 128) * 256 + n]);
  } else if (i < 131072) {               // Wt1_iu
    int j = i - 65536;
    int n = j >> 8, k = j & 255;
    Wt1_iu[j] = f2bf(k < 128 ? W1s_iu[k * 256 + n] : W1n_iu[(k - 128) * 256 + n]);
  } else if (i < 262144) {               // 4 x [128][256]
    int j = i - 131072;
    int reg = j >> 15;                   // 0..3
    int t = j & 32767;
    int n = t >> 8, k = t & 255;
    const float* src = (reg == 0) ? W2s_ui : (reg == 1) ? W2n_ui : (reg == 2) ? W2s_iu : W2n_iu;
    u16* dst = (reg == 0) ? Wt2s_ui : (reg == 1) ? Wt2n_ui : (reg == 2) ? Wt2s_iu : Wt2n_iu;
    dst[t] = f2bf(src[k * 128 + n]);
  }
}

// ==================== gather-mean (bf16 in -> bf16 out), one wave per dst row ====================
__global__ __launch_bounds__(256) void gather_mean(const u16* __restrict__ feat,
                                                   const int* __restrict__ off,
                                                   const int* __restrict__ csr,
                                                   u16* __restrict__ out, int n) {
  const int wid  = (blockIdx.x * blockDim.x + threadIdx.x) >> 6;
  const int lane = threadIdx.x & 63;
  if (wid >= n) return;
  const int j0 = off[wid], j1 = off[wid + 1];
  float ax = 0.f, ay = 0.f;
  for (int jb = j0; jb < j1; jb += 64) {
    int cnt = min(64, j1 - jb);
    int idx = (jb + lane < j1) ? csr[jb + lane] : 0;
    for (int t = 0; t < cnt; ++t) {
      int s = __shfl(idx, t);
      u32 v = *reinterpret_cast<const u32*>(feat + (size_t)s * 128 + (lane << 1));
      ax += __uint_as_float(v << 16);
      ay += __uint_as_float(v & 0xffff0000u);
    }
  }
  float r = 1.0f / fmaxf((float)(j1 - j0), 1.0f);
  u32 o = (u32)f2bf(ax * r) | ((u32)f2bf(ay * r) << 16);
  *reinterpret_cast<u32*>(out + (size_t)wid * 128 + (lane << 1)) = o;
}

// ==================== MFMA GEMM ====================
// C[M x N] = A[M x 256] @ W[256 x N], A bf16 (1 or 2 stacked-K tables), Bt = W^T [N][256] bf16.
// EPI 0: +bias, leaky, store bf16 (ldout)   [layer 1]
// EPI 1: store bf16 (ldout=128)             [projection]
// EPI 2: +bias +mean(bf16,[M][128]), store f32 (ldout=128)  [layer 2 final]
__device__ __forceinline__ void glds16(const void* g, void* l) {
  __builtin_amdgcn_global_load_lds((const __attribute__((address_space(1))) void*)g,
                                   (__attribute__((address_space(3))) void*)l, 16, 0, 0);
}

template<int NTAB, int EPI, int AST>
__global__ __launch_bounds__(256) void mfma_gemm(
    const u16* __restrict__ A0, const u16* __restrict__ A1,
    const u16* __restrict__ Bt,
    const float* __restrict__ bias,
    const u16* __restrict__ mean,
    void* __restrict__ outp,
    int M, int ldout)
{
  constexpr int K = 256, BK = 32, BM = 128;
  __shared__ __align__(16) u16 As[BM * BK];
  __shared__ __align__(16) u16 Bs[BM * BK];

  const int tid  = threadIdx.x;
  const int lane = tid & 63;
  const int w    = tid >> 6;
  const int wr   = w >> 1, wc = w & 1;
  const int gr0  = blockIdx.x * BM;
  const int gc0  = blockIdx.y * BM;

  f32x4 acc[4][4];
  #pragma unroll
  for (int m = 0; m < 4; ++m)
    #pragma unroll
    for (int n = 0; n < 4; ++n) acc[m][n] = (f32x4){0.f, 0.f, 0.f, 0.f};

  const int srow  = lane >> 2;   // 0..15 within a 16-row chunk
  const int sslot = lane & 3;    // 16B slot within 64B row

  for (int kt = 0; kt < K; kt += BK) {
    const u16* At = (NTAB == 2 && kt >= 128) ? A1 : A0;
    const int kbase = (NTAB == 2) ? (kt & 127) : kt;
    #pragma unroll
    for (int c = 0; c < 2; ++c) {
      int rl = w * 32 + c * 16 + srow;                 // LDS-local row 0..127
      int swz = (sslot ^ ((rl >> 1) & 3)) << 3;       // swizzled k-slot (elements)
      // A tile
      int grow = gr0 + rl; grow = grow < M ? grow : M - 1;
      glds16(At + (size_t)grow * AST + kbase + swz, As + (size_t)(w * 32 + c * 16) * BK);
      // B tile (Bt row = output col; N is exact multiple of 128)
      glds16(Bt + (size_t)(gc0 + rl) * K + kt + swz, Bs + (size_t)(w * 32 + c * 16) * BK);
    }
    __syncthreads();

    bf16x8 af[4], bfr[4];
    #pragma unroll
    for (int m = 0; m < 4; ++m) {
      int row = wr * 64 + m * 16 + (lane & 15);
      int idx = (row << 5) + ((((lane >> 4) ^ ((row >> 1) & 3))) << 3);
      af[m] = *reinterpret_cast<const bf16x8*>(As + idx);
    }
    #pragma unroll
    for (int n = 0; n < 4; ++n) {
      int row = wc * 64 + n * 16 + (lane & 15);
      int idx = (row << 5) + ((((lane >> 4) ^ ((row >> 1) & 3))) << 3);
      bfr[n] = *reinterpret_cast<const bf16x8*>(Bs + idx);
    }
    #pragma unroll
    for (int m = 0; m < 4; ++m)
      #pragma unroll
      for (int n = 0; n < 4; ++n)
        acc[m][n] = __builtin_amdgcn_mfma_f32_16x16x32_bf16(af[m], bfr[n], acc[m][n], 0, 0, 0);
    __syncthreads();
  }

  // epilogue: D col = lane&15, row = (lane>>4)*4 + r
  #pragma unroll
  for (int n = 0; n < 4; ++n) {
    int col = gc0 + wc * 64 + n * 16 + (lane & 15);
    float b = (EPI == 1) ? 0.f : bias[col];
    #pragma unroll
    for (int m = 0; m < 4; ++m) {
      int row0 = gr0 + wr * 64 + m * 16 + ((lane >> 4) << 2);
      #pragma unroll
      for (int r = 0; r < 4; ++r) {
        int row = row0 + r;
        if (row < M) {
          float v = acc[m][n][r] + b;
          if (EPI == 0) {
            v = (v >= 0.f) ? v : 0.01f * v;
            ((u16*)outp)[(size_t)row * ldout + col] = f2bf(v);
          } else if (EPI == 1) {
            ((u16*)outp)[(size_t)row * ldout + col] = f2bf(v);
          } else {
            v += bf2f(mean[(size_t)row * 128 + col]);
            ((float*)outp)[(size_t)row * ldout + col] = v;
          }
        }
      }
    }
  }
}

// ==================== launch ====================
extern "C" void kernel_launch(void* const* d_in, const int* in_sizes, int n_in,
                              void* d_out, int out_size, void* d_ws, size_t ws_size,
                              hipStream_t stream) {
  const float* emb_user    = (const float*)d_in[0];
  const float* emb_item    = (const float*)d_in[1];
  const float* W1_self_ui  = (const float*)d_in[2];
  const float* W1_neigh_ui = (const float*)d_in[3];
  const float* b1_ui       = (const float*)d_in[4];
  const float* W1_self_iu  = (const float*)d_in[5];
  const float* W1_neigh_iu = (const float*)d_in[6];
  const float* b1_iu       = (const float*)d_in[7];
  const float* W2_self_ui  = (const float*)d_in[8];
  const float* W2_neigh_ui = (const float*)d_in[9];
  const float* b2_ui       = (const float*)d_in[10];
  const float* W2_self_iu  = (const float*)d_in[11];
  const float* W2_neigh_iu = (const float*)d_in[12];
  const float* b2_iu       = (const float*)d_in[13];
  const int* e1_src = (const int*)d_in[14];
  const int* e1_dst = (const int*)d_in[15];
  const int* e2_src = (const int*)d_in[16];
  const int* e2_dst = (const int*)d_in[17];

  // ---- workspace ----
  u16* p16 = (u16*)d_ws;
  u16* ue    = p16; p16 += (size_t)NUc * 128;
  u16* ie    = p16; p16 += (size_t)NIc * 128;
  u16* h1i   = p16; p16 += (size_t)NIc * 256;
  u16* h1u   = p16; p16 += (size_t)NUc * 256;
  u16* aggb  = p16; p16 += (size_t)100000 * 128;
  u16* pbuf  = p16; p16 += (size_t)100000 * 128;
  u16* Wt1_ui  = p16; p16 += 256 * 256;
  u16* Wt1_iu  = p16; p16 += 256 * 256;
  u16* Wt2s_ui = p16; p16 += 128 * 256;
  u16* Wt2n_ui = p16; p16 += 128 * 256;
  u16* Wt2s_iu = p16; p16 += 128 * 256;
  u16* Wt2n_iu = p16; p16 += 128 * 256;
  int* ip    = (int*)p16;
  int* ideg1 = ip;  ip += NIc;
  int* ideg2 = ip;  ip += NUc;
  int* off1  = ip;  ip += NIc + 1;
  int* off2  = ip;  ip += NUc + 1;
  int* cur1  = ip;  ip += NIc;
  int* cur2  = ip;  ip += NUc;
  int* csr1  = ip;  ip += Ec;
  int* csr2  = ip;  ip += Ec;
  int* bsum1 = ip;  ip += 512;
  int* bscan1= ip;  ip += 512;
  int* bsum2 = ip;  ip += 512;
  int* bscan2= ip;  ip += 512;

  float* h2_user = (float*)d_out;
  float* h2_item = h2_user + (size_t)NUc * 128;

  dim3 blk(256);
  const int gatherBlocks = (100000 + 3) / 4;
  dim3 gemmL1(782, 2);
  dim3 gemmL2(782, 1);

  // ---- casts + weight prep ----
  cast_f32_bf16<<<1024, blk, 0, stream>>>(emb_user, ue, NUc * 128 / 4);
  cast_f32_bf16<<<1024, blk, 0, stream>>>(emb_item, ie, NIc * 128 / 4);
  prep_weights<<<1024, blk, 0, stream>>>(W1_self_ui, W1_neigh_ui, W1_self_iu, W1_neigh_iu,
                                         W2_self_ui, W2_neigh_ui, W2_self_iu, W2_neigh_iu,
                                         Wt1_ui, Wt1_iu, Wt2s_ui, Wt2n_ui, Wt2s_iu, Wt2n_iu);

  // ---- CSR build ----
  hipMemsetAsync(ideg1, 0, sizeof(int) * (size_t)(NIc + NUc), stream);
  hist_kernel<<<1024, blk, 0, stream>>>(e1_dst, e2_dst, ideg1, ideg2);

  block_reduce_kernel<<<NB, blk, 0, stream>>>(ideg1, bsum1, NIc);
  scan_bsums_kernel<<<1, 512, 0, stream>>>(bsum1, bscan1, NB);
  scan_blocks_kernel<<<NB, blk, 0, stream>>>(ideg1, bscan1, off1, NIc);
  init_cursor_kernel<<<NB, blk, 0, stream>>>(off1, cur1, NIc);

  block_reduce_kernel<<<NB, blk, 0, stream>>>(ideg2, bsum2, NUc);
  scan_bsums_kernel<<<1, 512, 0, stream>>>(bsum2, bscan2, NB);
  scan_blocks_kernel<<<NB, blk, 0, stream>>>(ideg2, bscan2, off2, NUc);
  init_cursor_kernel<<<NB, blk, 0, stream>>>(off2, cur2, NUc);

  fill_csr_kernel<<<1024, blk, 0, stream>>>(e1_src, e1_dst, e2_src, e2_dst,
                                            cur1, csr1, cur2, csr2);

  // ---- layer 1: items (mean of user emb) ----
  gather_mean<<<gatherBlocks, blk, 0, stream>>>(ue, off1, csr1, aggb, NIc);
  mfma_gemm<2, 0, 128><<<gemmL1, blk, 0, stream>>>(ie, aggb, Wt1_ui, b1_ui, nullptr,
                                                   h1i, Mrows, 256);
  // ---- layer 1: users (mean of item emb) ----
  gather_mean<<<gatherBlocks, blk, 0, stream>>>(ie, off2, csr2, aggb, NUc);
  mfma_gemm<2, 0, 128><<<gemmL1, blk, 0, stream>>>(ue, aggb, Wt1_iu, b1_iu, nullptr,
                                                   h1u, Mrows, 256);

  // ---- layer 2: items ----
  mfma_gemm<1, 1, 256><<<gemmL2, blk, 0, stream>>>(h1u, nullptr, Wt2n_ui, nullptr, nullptr,
                                                   pbuf, Mrows, 128);
  gather_mean<<<gatherBlocks, blk, 0, stream>>>(pbuf, off1, csr1, aggb, NIc);
  mfma_gemm<1, 2, 256><<<gemmL2, blk, 0, stream>>>(h1i, nullptr, Wt2s_ui, b2_ui, aggb,
                                                   h2_item, Mrows, 128);

  // ---- layer 2: users ----
  mfma_gemm<1, 1, 256><<<gemmL2, blk, 0, stream>>>(h1i, nullptr, Wt2n_iu, nullptr, nullptr,
                                                   pbuf, Mrows, 128);
  gather_mean<<<gatherBlocks, blk, 0, stream>>>(pbuf, off2, csr2, aggb, NUc);
  mfma_gemm<1, 2, 256><<<gemmL2, blk, 0, stream>>>(h1u, nullptr, Wt2s_iu, b2_iu, aggb,
                                                   h2_user, Mrows, 128);
}

// Round 4
// 455.547 us; speedup vs baseline: 9.1739x; 1.2602x over previous
//
#include <hip/hip_runtime.h>
#include <stdint.h>

typedef unsigned short u16;
typedef unsigned int   u32;
typedef __attribute__((ext_vector_type(8))) short bf16x8;
typedef __attribute__((ext_vector_type(4))) float f32x4;

constexpr int NUc = 100000;
constexpr int NIc = 100000;
constexpr int Ec  = 500000;
constexpr int Mrows = 100000;
constexpr int NB  = (100000 + 255) / 256;   // 391 scan blocks

__device__ __forceinline__ u16 f2bf(float f) {
  u32 u = __float_as_uint(f);
  u += 0x7fffu + ((u >> 16) & 1u);          // round-to-nearest-even
  return (u16)(u >> 16);
}
__device__ __forceinline__ float bf2f(u16 h) { return __uint_as_float(((u32)h) << 16); }

// ==================== fused cast + weight prep ====================
__global__ void prep_all(const float* __restrict__ eu, const float* __restrict__ ei,
                         const float* __restrict__ W1s_ui, const float* __restrict__ W1n_ui,
                         const float* __restrict__ W1s_iu, const float* __restrict__ W1n_iu,
                         const float* __restrict__ W2s_ui, const float* __restrict__ W2n_ui,
                         const float* __restrict__ W2s_iu, const float* __restrict__ W2n_iu,
                         u16* __restrict__ ue, u16* __restrict__ ie,
                         u16* __restrict__ Wt1_ui, u16* __restrict__ Wt1_iu,
                         u16* __restrict__ Wt2s_ui, u16* __restrict__ Wt2n_ui,
                         u16* __restrict__ Wt2s_iu, u16* __restrict__ Wt2n_iu) {
  constexpr int N4 = NUc * 128 / 4;          // 3.2M float4 chunks per table
  constexpr int TOT = 2 * N4 + 262144;
  int i = blockIdx.x * blockDim.x + threadIdx.x;
  const int stride = gridDim.x * blockDim.x;
  for (int t = i; t < TOT; t += stride) {
    if (t < 2 * N4) {
      const float* src = (t < N4) ? eu : ei;
      u16* dst = (t < N4) ? ue : ie;
      int c = (t < N4) ? t : t - N4;
      float4 v = reinterpret_cast<const float4*>(src)[c];
      ushort4 o;
      o.x = f2bf(v.x); o.y = f2bf(v.y); o.z = f2bf(v.z); o.w = f2bf(v.w);
      reinterpret_cast<ushort4*>(dst)[c] = o;
    } else {
      int j = t - 2 * N4;
      if (j < 65536) {                       // Wt1_ui [256][256]
        int n = j >> 8, k = j & 255;
        Wt1_ui[j] = f2bf(k < 128 ? W1s_ui[k * 256 + n] : W1n_ui[(k - 128) * 256 + n]);
      } else if (j < 131072) {               // Wt1_iu
        int q = j - 65536;
        int n = q >> 8, k = q & 255;
        Wt1_iu[q] = f2bf(k < 128 ? W1s_iu[k * 256 + n] : W1n_iu[(k - 128) * 256 + n]);
      } else {                               // 4 x [128][256]
        int q = j - 131072;
        int reg = q >> 15;
        int s = q & 32767;
        int n = s >> 8, k = s & 255;
        const float* src = (reg == 0) ? W2s_ui : (reg == 1) ? W2n_ui : (reg == 2) ? W2s_iu : W2n_iu;
        u16* dst = (reg == 0) ? Wt2s_ui : (reg == 1) ? Wt2n_ui : (reg == 2) ? Wt2s_iu : Wt2n_iu;
        dst[s] = f2bf(src[k * 128 + n]);
      }
    }
  }
}

// ==================== CSR build ====================
__global__ void hist_kernel(const int* __restrict__ e1_dst, const int* __restrict__ e2_dst,
                            int* __restrict__ ideg1, int* __restrict__ ideg2,
                            int* __restrict__ rank1, int* __restrict__ rank2) {
  int i = blockIdx.x * blockDim.x + threadIdx.x;
  const int stride = gridDim.x * blockDim.x;
  for (; i < 2 * Ec; i += stride) {
    if (i < Ec) rank1[i] = atomicAdd(&ideg1[e1_dst[i]], 1);
    else        rank2[i - Ec] = atomicAdd(&ideg2[e2_dst[i - Ec]], 1);
  }
}

__global__ void block_reduce2(const int* __restrict__ ideg1, const int* __restrict__ ideg2,
                              int* __restrict__ bsum1, int* __restrict__ bsum2, int n) {
  const int* deg = blockIdx.y ? ideg2 : ideg1;
  int* bsum = blockIdx.y ? bsum2 : bsum1;
  __shared__ int s[256];
  int t = threadIdx.x, i = blockIdx.x * 256 + t;
  s[t] = (i < n) ? deg[i] : 0;
  __syncthreads();
  for (int st = 128; st > 0; st >>= 1) { if (t < st) s[t] += s[t + st]; __syncthreads(); }
  if (t == 0) bsum[blockIdx.x] = s[0];
}

__global__ void scan_bsums2(const int* __restrict__ bsum1, const int* __restrict__ bsum2,
                            int* __restrict__ bscan1, int* __restrict__ bscan2, int nb) {
  const int* bsum = blockIdx.x ? bsum2 : bsum1;
  int* bscan = blockIdx.x ? bscan2 : bscan1;
  __shared__ int s[512];
  int t = threadIdx.x;
  int v0 = (t < nb) ? bsum[t] : 0;
  s[t] = v0;
  __syncthreads();
  for (int d = 1; d < 512; d <<= 1) {
    int v = (t >= d) ? s[t - d] : 0;
    __syncthreads();
    s[t] += v;
    __syncthreads();
  }
  if (t < nb) bscan[t] = s[t] - v0;   // exclusive
}

__global__ void scan_blocks2(const int* __restrict__ ideg1, const int* __restrict__ ideg2,
                             const int* __restrict__ bscan1, const int* __restrict__ bscan2,
                             int* __restrict__ off1, int* __restrict__ off2, int n) {
  const int* deg = blockIdx.y ? ideg2 : ideg1;
  const int* bscan = blockIdx.y ? bscan2 : bscan1;
  int* off = blockIdx.y ? off2 : off1;
  __shared__ int s[256];
  int t = threadIdx.x, i = blockIdx.x * 256 + t;
  int d = (i < n) ? deg[i] : 0;
  s[t] = d;
  __syncthreads();
  for (int st = 1; st < 256; st <<= 1) {
    int v = (t >= st) ? s[t - st] : 0;
    __syncthreads();
    s[t] += v;
    __syncthreads();
  }
  if (i < n) off[i] = bscan[blockIdx.x] + s[t] - d;
  if (i == 0) off[n] = Ec;
}

__global__ void fill_csr_kernel(const int* __restrict__ e1_src, const int* __restrict__ e1_dst,
                                const int* __restrict__ e2_src, const int* __restrict__ e2_dst,
                                const int* __restrict__ rank1, const int* __restrict__ rank2,
                                const int* __restrict__ off1, const int* __restrict__ off2,
                                int* __restrict__ csr1, int* __restrict__ csr2) {
  int i = blockIdx.x * blockDim.x + threadIdx.x;
  const int stride = gridDim.x * blockDim.x;
  for (; i < 2 * Ec; i += stride) {
    if (i < Ec) {
      int d = e1_dst[i];
      csr1[off1[d] + rank1[i]] = e1_src[i];
    } else {
      int e = i - Ec;
      int d = e2_dst[e];
      csr2[off2[d] + rank2[e]] = e2_src[e];
    }
  }
}

// ==================== gather-mean x2 segments (bf16 -> bf16), one wave per dst row ====================
__global__ __launch_bounds__(256) void gather2(const u16* __restrict__ fA, const int* __restrict__ offA,
                                               const int* __restrict__ csrA, u16* __restrict__ outA,
                                               const u16* __restrict__ fB, const int* __restrict__ offB,
                                               const int* __restrict__ csrB, u16* __restrict__ outB) {
  const int wid  = (blockIdx.x * blockDim.x + threadIdx.x) >> 6;
  const int lane = threadIdx.x & 63;
  const u16* f; const int* off; const int* csr; u16* out; int r;
  if (wid < 100000)      { f = fA; off = offA; csr = csrA; out = outA; r = wid; }
  else if (wid < 200000) { f = fB; off = offB; csr = csrB; out = outB; r = wid - 100000; }
  else return;
  const int j0 = off[r], j1 = off[r + 1];
  const int colb = lane << 1;
  float ax = 0.f, ay = 0.f;
  for (int jb = j0; jb < j1; jb += 64) {
    int cnt = min(64, j1 - jb);
    int idx = (jb + lane < j1) ? csr[jb + lane] : 0;
    int t = 0;
    for (; t + 2 <= cnt; t += 2) {
      int s0 = __shfl(idx, t), s1 = __shfl(idx, t + 1);
      u32 v0 = *reinterpret_cast<const u32*>(f + (size_t)s0 * 128 + colb);
      u32 v1 = *reinterpret_cast<const u32*>(f + (size_t)s1 * 128 + colb);
      ax += __uint_as_float(v0 << 16);
      ay += __uint_as_float(v0 & 0xffff0000u);
      ax += __uint_as_float(v1 << 16);
      ay += __uint_as_float(v1 & 0xffff0000u);
    }
    if (t < cnt) {
      int s0 = __shfl(idx, t);
      u32 v0 = *reinterpret_cast<const u32*>(f + (size_t)s0 * 128 + colb);
      ax += __uint_as_float(v0 << 16);
      ay += __uint_as_float(v0 & 0xffff0000u);
    }
  }
  float rs = 1.0f / fmaxf((float)(j1 - j0), 1.0f);
  u32 o = (u32)f2bf(ax * rs) | ((u32)f2bf(ay * rs) << 16);
  *reinterpret_cast<u32*>(out + (size_t)r * 128 + colb) = o;
}

// ==================== MFMA GEMM, z-batched (2 problem instances) ====================
// C[M x N] = A[M x 256] @ W[256 x N]; A bf16 (1 or 2 stacked-K tables), Bt = W^T [N][256] bf16.
// EPI 0: +bias, leaky, store bf16        [layer 1]
// EPI 1: store bf16                      [projection]
// EPI 2: +bias +mean(bf16), store f32    [layer 2 final]
__device__ __forceinline__ void glds16(const void* g, void* l) {
  __builtin_amdgcn_global_load_lds((const __attribute__((address_space(1))) void*)g,
                                   (__attribute__((address_space(3))) void*)l, 16, 0, 0);
}

template<int NTAB, int EPI, int AST>
__global__ __launch_bounds__(256) void mfma_gemm2(
    const u16* __restrict__ A0a, const u16* __restrict__ A1a, const u16* __restrict__ Bta,
    const float* __restrict__ biasa, const u16* __restrict__ meana, void* __restrict__ outa,
    const u16* __restrict__ A0b, const u16* __restrict__ A1b, const u16* __restrict__ Btb,
    const float* __restrict__ biasb, const u16* __restrict__ meanb, void* __restrict__ outb,
    int M, int ldout)
{
  constexpr int K = 256, BK = 32, BM = 128;
  __shared__ __align__(16) u16 As[BM * BK];
  __shared__ __align__(16) u16 Bs[BM * BK];

  const bool zb = (blockIdx.z != 0);
  const u16* A0 = zb ? A0b : A0a;
  const u16* A1 = zb ? A1b : A1a;
  const u16* Bt = zb ? Btb : Bta;
  const float* bias = zb ? biasb : biasa;
  const u16* mean = zb ? meanb : meana;
  void* outp = zb ? outb : outa;

  const int tid  = threadIdx.x;
  const int lane = tid & 63;
  const int w    = tid >> 6;
  const int wr   = w >> 1, wc = w & 1;
  const int gr0  = blockIdx.x * BM;
  const int gc0  = blockIdx.y * BM;

  f32x4 acc[4][4];
  #pragma unroll
  for (int m = 0; m < 4; ++m)
    #pragma unroll
    for (int n = 0; n < 4; ++n) acc[m][n] = (f32x4){0.f, 0.f, 0.f, 0.f};

  const int srow  = lane >> 2;   // 0..15 within a 16-row chunk
  const int sslot = lane & 3;    // 16B slot within 64B row

  for (int kt = 0; kt < K; kt += BK) {
    const u16* At = (NTAB == 2 && kt >= 128) ? A1 : A0;
    const int kbase = (NTAB == 2) ? (kt & 127) : kt;
    #pragma unroll
    for (int c = 0; c < 2; ++c) {
      int rl = w * 32 + c * 16 + srow;                 // LDS-local row 0..127
      int swz = (sslot ^ ((rl >> 1) & 3)) << 3;        // swizzled k-slot (elements)
      int grow = gr0 + rl; grow = grow < M ? grow : M - 1;
      glds16(At + (size_t)grow * AST + kbase + swz, As + (size_t)(w * 32 + c * 16) * BK);
      glds16(Bt + (size_t)(gc0 + rl) * K + kt + swz, Bs + (size_t)(w * 32 + c * 16) * BK);
    }
    __syncthreads();

    bf16x8 af[4], bfr[4];
    #pragma unroll
    for (int m = 0; m < 4; ++m) {
      int row = wr * 64 + m * 16 + (lane & 15);
      int idx = (row << 5) + ((((lane >> 4) ^ ((row >> 1) & 3))) << 3);
      af[m] = *reinterpret_cast<const bf16x8*>(As + idx);
    }
    #pragma unroll
    for (int n = 0; n < 4; ++n) {
      int row = wc * 64 + n * 16 + (lane & 15);
      int idx = (row << 5) + ((((lane >> 4) ^ ((row >> 1) & 3))) << 3);
      bfr[n] = *reinterpret_cast<const bf16x8*>(Bs + idx);
    }
    #pragma unroll
    for (int m = 0; m < 4; ++m)
      #pragma unroll
      for (int n = 0; n < 4; ++n)
        acc[m][n] = __builtin_amdgcn_mfma_f32_16x16x32_bf16(af[m], bfr[n], acc[m][n], 0, 0, 0);
    __syncthreads();
  }

  // epilogue: D col = lane&15, row = (lane>>4)*4 + r
  #pragma unroll
  for (int n = 0; n < 4; ++n) {
    int col = gc0 + wc * 64 + n * 16 + (lane & 15);
    float b = (EPI == 1) ? 0.f : bias[col];
    #pragma unroll
    for (int m = 0; m < 4; ++m) {
      int row0 = gr0 + wr * 64 + m * 16 + ((lane >> 4) << 2);
      #pragma unroll
      for (int r = 0; r < 4; ++r) {
        int row = row0 + r;
        if (row < M) {
          float v = acc[m][n][r] + b;
          if (EPI == 0) {
            v = (v >= 0.f) ? v : 0.01f * v;
            ((u16*)outp)[(size_t)row * ldout + col] = f2bf(v);
          } else if (EPI == 1) {
            ((u16*)outp)[(size_t)row * ldout + col] = f2bf(v);
          } else {
            v += bf2f(mean[(size_t)row * 128 + col]);
            ((float*)outp)[(size_t)row * ldout + col] = v;
          }
        }
      }
    }
  }
}

// ==================== launch ====================
extern "C" void kernel_launch(void* const* d_in, const int* in_sizes, int n_in,
                              void* d_out, int out_size, void* d_ws, size_t ws_size,
                              hipStream_t stream) {
  const float* emb_user    = (const float*)d_in[0];
  const float* emb_item    = (const float*)d_in[1];
  const float* W1_self_ui  = (const float*)d_in[2];
  const float* W1_neigh_ui = (const float*)d_in[3];
  const float* b1_ui       = (const float*)d_in[4];
  const float* W1_self_iu  = (const float*)d_in[5];
  const float* W1_neigh_iu = (const float*)d_in[6];
  const float* b1_iu       = (const float*)d_in[7];
  const float* W2_self_ui  = (const float*)d_in[8];
  const float* W2_neigh_ui = (const float*)d_in[9];
  const float* b2_ui       = (const float*)d_in[10];
  const float* W2_self_iu  = (const float*)d_in[11];
  const float* W2_neigh_iu = (const float*)d_in[12];
  const float* b2_iu       = (const float*)d_in[13];
  const int* e1_src = (const int*)d_in[14];
  const int* e1_dst = (const int*)d_in[15];
  const int* e2_src = (const int*)d_in[16];
  const int* e2_dst = (const int*)d_in[17];

  // ---- workspace ----
  u16* p16 = (u16*)d_ws;
  u16* ue     = p16; p16 += (size_t)NUc * 128;
  u16* ie     = p16; p16 += (size_t)NIc * 128;
  u16* h1i    = p16; p16 += (size_t)NIc * 256;
  u16* h1u    = p16; p16 += (size_t)NUc * 256;
  u16* aggb_i = p16; p16 += (size_t)NIc * 128;
  u16* aggb_u = p16; p16 += (size_t)NUc * 128;
  u16* pbuf_i = p16; p16 += (size_t)NUc * 128;
  u16* pbuf_u = p16; p16 += (size_t)NIc * 128;
  u16* Wt1_ui  = p16; p16 += 256 * 256;
  u16* Wt1_iu  = p16; p16 += 256 * 256;
  u16* Wt2s_ui = p16; p16 += 128 * 256;
  u16* Wt2n_ui = p16; p16 += 128 * 256;
  u16* Wt2s_iu = p16; p16 += 128 * 256;
  u16* Wt2n_iu = p16; p16 += 128 * 256;
  int* ip    = (int*)p16;
  int* ideg1 = ip;  ip += NIc;
  int* ideg2 = ip;  ip += NUc;
  int* off1  = ip;  ip += NIc + 1;
  int* off2  = ip;  ip += NUc + 1;
  int* rank1 = ip;  ip += Ec;
  int* rank2 = ip;  ip += Ec;
  int* csr1  = ip;  ip += Ec;
  int* csr2  = ip;  ip += Ec;
  int* bsum1 = ip;  ip += 512;
  int* bscan1= ip;  ip += 512;
  int* bsum2 = ip;  ip += 512;
  int* bscan2= ip;  ip += 512;

  float* h2_user = (float*)d_out;
  float* h2_item = h2_user + (size_t)NUc * 128;

  dim3 blk(256);
  const int gather2Blocks = (200000 + 3) / 4;
  dim3 gemmL1(782, 2, 2);
  dim3 gemmL2(782, 1, 2);

  // ---- prep: casts + weights, CSR ----
  hipMemsetAsync(ideg1, 0, sizeof(int) * (size_t)(NIc + NUc), stream);
  prep_all<<<4096, blk, 0, stream>>>(emb_user, emb_item,
                                     W1_self_ui, W1_neigh_ui, W1_self_iu, W1_neigh_iu,
                                     W2_self_ui, W2_neigh_ui, W2_self_iu, W2_neigh_iu,
                                     ue, ie, Wt1_ui, Wt1_iu, Wt2s_ui, Wt2n_ui, Wt2s_iu, Wt2n_iu);
  hist_kernel<<<1024, blk, 0, stream>>>(e1_dst, e2_dst, ideg1, ideg2, rank1, rank2);
  block_reduce2<<<dim3(NB, 2), blk, 0, stream>>>(ideg1, ideg2, bsum1, bsum2, NIc);
  scan_bsums2<<<2, 512, 0, stream>>>(bsum1, bsum2, bscan1, bscan2, NB);
  scan_blocks2<<<dim3(NB, 2), blk, 0, stream>>>(ideg1, ideg2, bscan1, bscan2, off1, off2, NIc);
  fill_csr_kernel<<<1024, blk, 0, stream>>>(e1_src, e1_dst, e2_src, e2_dst,
                                            rank1, rank2, off1, off2, csr1, csr2);

  // ---- layer 1: both relations ----
  gather2<<<gather2Blocks, blk, 0, stream>>>(ue, off1, csr1, aggb_i,
                                             ie, off2, csr2, aggb_u);
  mfma_gemm2<2, 0, 128><<<gemmL1, blk, 0, stream>>>(
      ie, aggb_i, Wt1_ui, b1_ui, nullptr, h1i,
      ue, aggb_u, Wt1_iu, b1_iu, nullptr, h1u, Mrows, 256);

  // ---- layer 2: projections (h1u->pbuf_i via W2n_ui, h1i->pbuf_u via W2n_iu) ----
  mfma_gemm2<1, 1, 256><<<gemmL2, blk, 0, stream>>>(
      h1u, nullptr, Wt2n_ui, nullptr, nullptr, pbuf_i,
      h1i, nullptr, Wt2n_iu, nullptr, nullptr, pbuf_u, Mrows, 128);

  // ---- layer 2: gathers ----
  gather2<<<gather2Blocks, blk, 0, stream>>>(pbuf_i, off1, csr1, aggb_i,
                                             pbuf_u, off2, csr2, aggb_u);

  // ---- layer 2: final ----
  mfma_gemm2<1, 2, 256><<<gemmL2, blk, 0, stream>>>(
      h1i, nullptr, Wt2s_ui, b2_ui, aggb_i, h2_item,
      h1u, nullptr, Wt2s_iu, b2_iu, aggb_u, h2_user, Mrows, 128);
}

// Round 5
// 390.320 us; speedup vs baseline: 10.7070x; 1.1671x over previous
//
#include <hip/hip_runtime.h>
#include <stdint.h>

typedef unsigned short u16;
typedef unsigned int   u32;
typedef __attribute__((ext_vector_type(8))) short bf16x8;
typedef __attribute__((ext_vector_type(4))) float f32x4;
typedef __attribute__((ext_vector_type(8))) unsigned short u16x8;

constexpr int NUc = 100000;
constexpr int NIc = 100000;
constexpr int Ec  = 500000;
constexpr int Mrows = 100000;
constexpr int NB  = (100000 + 255) / 256;   // 391 scan blocks

__device__ __forceinline__ u16 f2bf(float f) {
  u32 u = __float_as_uint(f);
  u += 0x7fffu + ((u >> 16) & 1u);          // round-to-nearest-even
  return (u16)(u >> 16);
}
__device__ __forceinline__ float bf2f(u16 h) { return __uint_as_float(((u32)h) << 16); }

// ==================== fused cast + weight prep ====================
// Wt1_*  [256 outcol][256 k]  : k<128 -> W1_self^T, k>=128 -> W1_neigh^T
// Wt2c_u [256 outcol][256 k]  : col<128 -> W2n_ui^T (proj_u2i), col>=128 -> W2s_iu^T (self_u)
// Wt2c_i [256 outcol][256 k]  : col<128 -> W2n_iu^T (proj_i2u), col>=128 -> W2s_ui^T (self_i)
__global__ void prep_all(const float* __restrict__ eu, const float* __restrict__ ei,
                         const float* __restrict__ W1s_ui, const float* __restrict__ W1n_ui,
                         const float* __restrict__ W1s_iu, const float* __restrict__ W1n_iu,
                         const float* __restrict__ W2s_ui, const float* __restrict__ W2n_ui,
                         const float* __restrict__ W2s_iu, const float* __restrict__ W2n_iu,
                         u16* __restrict__ ue, u16* __restrict__ ie,
                         u16* __restrict__ Wt1_ui, u16* __restrict__ Wt1_iu,
                         u16* __restrict__ Wt2c_u, u16* __restrict__ Wt2c_i) {
  constexpr int N4 = NUc * 128 / 4;
  constexpr int TOT = 2 * N4 + 262144;
  int i = blockIdx.x * blockDim.x + threadIdx.x;
  const int stride = gridDim.x * blockDim.x;
  for (int t = i; t < TOT; t += stride) {
    if (t < 2 * N4) {
      const float* src = (t < N4) ? eu : ei;
      u16* dst = (t < N4) ? ue : ie;
      int c = (t < N4) ? t : t - N4;
      float4 v = reinterpret_cast<const float4*>(src)[c];
      ushort4 o;
      o.x = f2bf(v.x); o.y = f2bf(v.y); o.z = f2bf(v.z); o.w = f2bf(v.w);
      reinterpret_cast<ushort4*>(dst)[c] = o;
    } else {
      int j = t - 2 * N4;
      if (j < 131072) {                      // Wt1
        const float* Ws = (j < 65536) ? W1s_ui : W1s_iu;
        const float* Wn = (j < 65536) ? W1n_ui : W1n_iu;
        u16* dst = (j < 65536) ? Wt1_ui : Wt1_iu;
        int q = j & 65535;
        int n = q >> 8, k = q & 255;
        dst[q] = f2bf(k < 128 ? Ws[k * 256 + n] : Wn[(k - 128) * 256 + n]);
      } else {                               // Wt2c
        int q = j - 131072;
        int which = q >> 16;                 // 0: A=h1u set, 1: A=h1i set
        int s = q & 65535;
        int c = s >> 8, k = s & 255;
        float v;
        if (which == 0) v = (c < 128) ? W2n_ui[k * 128 + c] : W2s_iu[k * 128 + (c - 128)];
        else            v = (c < 128) ? W2n_iu[k * 128 + c] : W2s_ui[k * 128 + (c - 128)];
        u16* dst = which ? Wt2c_i : Wt2c_u;
        dst[s] = f2bf(v);
      }
    }
  }
}

// ==================== CSR build ====================
__global__ void hist_kernel(const int* __restrict__ e1_dst, const int* __restrict__ e2_dst,
                            int* __restrict__ ideg1, int* __restrict__ ideg2,
                            int* __restrict__ rank1, int* __restrict__ rank2) {
  int i = blockIdx.x * blockDim.x + threadIdx.x;
  const int stride = gridDim.x * blockDim.x;
  for (; i < 2 * Ec; i += stride) {
    if (i < Ec) rank1[i] = atomicAdd(&ideg1[e1_dst[i]], 1);
    else        rank2[i - Ec] = atomicAdd(&ideg2[e2_dst[i - Ec]], 1);
  }
}

__global__ void block_reduce2(const int* __restrict__ ideg1, const int* __restrict__ ideg2,
                              int* __restrict__ bsum1, int* __restrict__ bsum2, int n) {
  const int* deg = blockIdx.y ? ideg2 : ideg1;
  int* bsum = blockIdx.y ? bsum2 : bsum1;
  __shared__ int s[256];
  int t = threadIdx.x, i = blockIdx.x * 256 + t;
  s[t] = (i < n) ? deg[i] : 0;
  __syncthreads();
  for (int st = 128; st > 0; st >>= 1) { if (t < st) s[t] += s[t + st]; __syncthreads(); }
  if (t == 0) bsum[blockIdx.x] = s[0];
}

__global__ void scan_bsums2(const int* __restrict__ bsum1, const int* __restrict__ bsum2,
                            int* __restrict__ bscan1, int* __restrict__ bscan2, int nb) {
  const int* bsum = blockIdx.x ? bsum2 : bsum1;
  int* bscan = blockIdx.x ? bscan2 : bscan1;
  __shared__ int s[512];
  int t = threadIdx.x;
  int v0 = (t < nb) ? bsum[t] : 0;
  s[t] = v0;
  __syncthreads();
  for (int d = 1; d < 512; d <<= 1) {
    int v = (t >= d) ? s[t - d] : 0;
    __syncthreads();
    s[t] += v;
    __syncthreads();
  }
  if (t < nb) bscan[t] = s[t] - v0;   // exclusive
}

__global__ void scan_blocks2(const int* __restrict__ ideg1, const int* __restrict__ ideg2,
                             const int* __restrict__ bscan1, const int* __restrict__ bscan2,
                             int* __restrict__ off1, int* __restrict__ off2, int n) {
  const int* deg = blockIdx.y ? ideg2 : ideg1;
  const int* bscan = blockIdx.y ? bscan2 : bscan1;
  int* off = blockIdx.y ? off2 : off1;
  __shared__ int s[256];
  int t = threadIdx.x, i = blockIdx.x * 256 + t;
  int d = (i < n) ? deg[i] : 0;
  s[t] = d;
  __syncthreads();
  for (int st = 1; st < 256; st <<= 1) {
    int v = (t >= st) ? s[t - st] : 0;
    __syncthreads();
    s[t] += v;
    __syncthreads();
  }
  if (i < n) off[i] = bscan[blockIdx.x] + s[t] - d;
  if (i == 0) off[n] = Ec;
}

__global__ void fill_csr_kernel(const int* __restrict__ e1_src, const int* __restrict__ e1_dst,
                                const int* __restrict__ e2_src, const int* __restrict__ e2_dst,
                                const int* __restrict__ rank1, const int* __restrict__ rank2,
                                const int* __restrict__ off1, const int* __restrict__ off2,
                                int* __restrict__ csr1, int* __restrict__ csr2) {
  int i = blockIdx.x * blockDim.x + threadIdx.x;
  const int stride = gridDim.x * blockDim.x;
  for (; i < 2 * Ec; i += stride) {
    if (i < Ec) {
      int d = e1_dst[i];
      csr1[off1[d] + rank1[i]] = e1_src[i];
    } else {
      int e = i - Ec;
      int d = e2_dst[e];
      csr2[off2[d] + rank2[e]] = e2_src[e];
    }
  }
}

// ==================== gather-mean x2 segments (bf16 -> bf16), one wave per dst row ====================
__global__ __launch_bounds__(256) void gather2(const u16* __restrict__ fA, const int* __restrict__ offA,
                                               const int* __restrict__ csrA, u16* __restrict__ outA,
                                               const u16* __restrict__ fB, const int* __restrict__ offB,
                                               const int* __restrict__ csrB, u16* __restrict__ outB) {
  const int wid  = (blockIdx.x * blockDim.x + threadIdx.x) >> 6;
  const int lane = threadIdx.x & 63;
  const u16* f; const int* off; const int* csr; u16* out; int r;
  if (wid < 100000)      { f = fA; off = offA; csr = csrA; out = outA; r = wid; }
  else if (wid < 200000) { f = fB; off = offB; csr = csrB; out = outB; r = wid - 100000; }
  else return;
  const int j0 = off[r], j1 = off[r + 1];
  const int colb = lane << 1;
  float ax = 0.f, ay = 0.f;
  for (int jb = j0; jb < j1; jb += 64) {
    int cnt = min(64, j1 - jb);
    int idx = (jb + lane < j1) ? csr[jb + lane] : 0;
    int t = 0;
    for (; t + 2 <= cnt; t += 2) {
      int s0 = __shfl(idx, t), s1 = __shfl(idx, t + 1);
      u32 v0 = *reinterpret_cast<const u32*>(f + (size_t)s0 * 128 + colb);
      u32 v1 = *reinterpret_cast<const u32*>(f + (size_t)s1 * 128 + colb);
      ax += __uint_as_float(v0 << 16);
      ay += __uint_as_float(v0 & 0xffff0000u);
      ax += __uint_as_float(v1 << 16);
      ay += __uint_as_float(v1 & 0xffff0000u);
    }
    if (t < cnt) {
      int s0 = __shfl(idx, t);
      u32 v0 = *reinterpret_cast<const u32*>(f + (size_t)s0 * 128 + colb);
      ax += __uint_as_float(v0 << 16);
      ay += __uint_as_float(v0 & 0xffff0000u);
    }
  }
  float rs = 1.0f / fmaxf((float)(j1 - j0), 1.0f);
  u32 o = (u32)f2bf(ax * rs) | ((u32)f2bf(ay * rs) << 16);
  *reinterpret_cast<u32*>(out + (size_t)r * 128 + colb) = o;
}

// ==================== final gather: out_f32 = bf16(self) + mean(proj[csr]) ====================
__global__ __launch_bounds__(256) void gather_final(
    const u16* __restrict__ pA, const int* __restrict__ offA, const int* __restrict__ csrA,
    const u16* __restrict__ sA, float* __restrict__ oA,
    const u16* __restrict__ pB, const int* __restrict__ offB, const int* __restrict__ csrB,
    const u16* __restrict__ sB, float* __restrict__ oB) {
  const int wid  = (blockIdx.x * blockDim.x + threadIdx.x) >> 6;
  const int lane = threadIdx.x & 63;
  const u16* f; const int* off; const int* csr; const u16* sf; float* out; int r;
  if (wid < 100000)      { f = pA; off = offA; csr = csrA; sf = sA; out = oA; r = wid; }
  else if (wid < 200000) { f = pB; off = offB; csr = csrB; sf = sB; out = oB; r = wid - 100000; }
  else return;
  const int j0 = off[r], j1 = off[r + 1];
  const int colb = lane << 1;
  float ax = 0.f, ay = 0.f;
  for (int jb = j0; jb < j1; jb += 64) {
    int cnt = min(64, j1 - jb);
    int idx = (jb + lane < j1) ? csr[jb + lane] : 0;
    int t = 0;
    for (; t + 2 <= cnt; t += 2) {
      int s0 = __shfl(idx, t), s1 = __shfl(idx, t + 1);
      u32 v0 = *reinterpret_cast<const u32*>(f + (size_t)s0 * 128 + colb);
      u32 v1 = *reinterpret_cast<const u32*>(f + (size_t)s1 * 128 + colb);
      ax += __uint_as_float(v0 << 16);
      ay += __uint_as_float(v0 & 0xffff0000u);
      ax += __uint_as_float(v1 << 16);
      ay += __uint_as_float(v1 & 0xffff0000u);
    }
    if (t < cnt) {
      int s0 = __shfl(idx, t);
      u32 v0 = *reinterpret_cast<const u32*>(f + (size_t)s0 * 128 + colb);
      ax += __uint_as_float(v0 << 16);
      ay += __uint_as_float(v0 & 0xffff0000u);
    }
  }
  float rs = 1.0f / fmaxf((float)(j1 - j0), 1.0f);
  u32 sv = *reinterpret_cast<const u32*>(sf + (size_t)r * 128 + colb);
  float2 o;
  o.x = ax * rs + __uint_as_float(sv << 16);
  o.y = ay * rs + __uint_as_float(sv & 0xffff0000u);
  *reinterpret_cast<float2*>(out + (size_t)r * 128 + colb) = o;
}

// ==================== MFMA GEMM, z-batched, LDS-coalesced epilogue ====================
// EPI 0: h1 = leaky([X;S]@W1 + b1), single bf16 out (ldout 256), grid.y = col-tile
// EPI 1: dual out (ldout 128): y=0 -> out0 = A@Wn (no bias); y=1 -> out1 = A@Ws + bias
__device__ __forceinline__ void glds16(const void* g, void* l) {
  __builtin_amdgcn_global_load_lds((const __attribute__((address_space(1))) void*)g,
                                   (__attribute__((address_space(3))) void*)l, 16, 0, 0);
}

template<int NTAB, int EPI, int AST>
__global__ __launch_bounds__(256) void mfma_gemm2(
    const u16* __restrict__ A0a, const u16* __restrict__ A1a, const u16* __restrict__ Bta,
    const float* __restrict__ biasa, u16* __restrict__ out0a, u16* __restrict__ out1a,
    const u16* __restrict__ A0b, const u16* __restrict__ A1b, const u16* __restrict__ Btb,
    const float* __restrict__ biasb, u16* __restrict__ out0b, u16* __restrict__ out1b,
    int M)
{
  constexpr int K = 256, BK = 32, BM = 128;
  __shared__ __align__(16) u16 smem[8192];   // As: [0,4096) Bs: [4096,8192); epilogue Ct: all 16KB
  u16* As = smem;
  u16* Bs = smem + 4096;

  const bool zb = (blockIdx.z != 0);
  const u16* A0 = zb ? A0b : A0a;
  const u16* A1 = zb ? A1b : A1a;
  const u16* Bt = zb ? Btb : Bta;
  const float* bias = zb ? biasb : biasa;

  const int tid  = threadIdx.x;
  const int lane = tid & 63;
  const int w    = tid >> 6;
  const int wr   = w >> 1, wc = w & 1;
  const int gr0  = blockIdx.x * BM;
  const int gc0  = blockIdx.y * BM;

  f32x4 acc[4][4];
  #pragma unroll
  for (int m = 0; m < 4; ++m)
    #pragma unroll
    for (int n = 0; n < 4; ++n) acc[m][n] = (f32x4){0.f, 0.f, 0.f, 0.f};

  const int srow  = lane >> 2;   // 0..15 within a 16-row chunk
  const int sslot = lane & 3;    // 16B slot within 64B row

  for (int kt = 0; kt < K; kt += BK) {
    const u16* At = (NTAB == 2 && kt >= 128) ? A1 : A0;
    const int kbase = (NTAB == 2) ? (kt & 127) : kt;
    #pragma unroll
    for (int c = 0; c < 2; ++c) {
      int rl = w * 32 + c * 16 + srow;                 // LDS-local row 0..127
      int swz = (sslot ^ ((rl >> 1) & 3)) << 3;        // swizzled k-slot (elements)
      int grow = gr0 + rl; grow = grow < M ? grow : M - 1;
      glds16(At + (size_t)grow * AST + kbase + swz, As + (size_t)(w * 32 + c * 16) * BK);
      glds16(Bt + (size_t)(gc0 + rl) * K + kt + swz, Bs + (size_t)(w * 32 + c * 16) * BK);
    }
    __syncthreads();

    bf16x8 af[4], bfr[4];
    #pragma unroll
    for (int m = 0; m < 4; ++m) {
      int row = wr * 64 + m * 16 + (lane & 15);
      int idx = (row << 5) + ((((lane >> 4) ^ ((row >> 1) & 3))) << 3);
      af[m] = *reinterpret_cast<const bf16x8*>(As + idx);
    }
    #pragma unroll
    for (int n = 0; n < 4; ++n) {
      int row = wc * 64 + n * 16 + (lane & 15);
      int idx = (row << 5) + ((((lane >> 4) ^ ((row >> 1) & 3))) << 3);
      bfr[n] = *reinterpret_cast<const bf16x8*>(Bs + idx);
    }
    #pragma unroll
    for (int m = 0; m < 4; ++m)
      #pragma unroll
      for (int n = 0; n < 4; ++n)
        acc[m][n] = __builtin_amdgcn_mfma_f32_16x16x32_bf16(af[m], bfr[n], acc[m][n], 0, 0, 0);
    __syncthreads();
  }

  // ---- epilogue: acc -> LDS slab (64 rows x 128 cols bf16) -> coalesced 16B stores ----
  u16* outp;
  if (EPI == 0) outp = zb ? out0b : out0a;
  else          outp = (blockIdx.y == 0) ? (zb ? out0b : out0a) : (zb ? out1b : out1a);
  const bool useBias = (EPI == 0) || (blockIdx.y == 1);

  const int cLane = lane & 15;
  const int rGrp  = (lane >> 4) << 2;
  for (int s = 0; s < 2; ++s) {
    if (wr == s) {
      #pragma unroll
      for (int n = 0; n < 4; ++n) {
        int lc = wc * 64 + n * 16 + cLane;             // 0..127 local col
        float b = 0.f;
        if (useBias) b = (EPI == 0) ? bias[gc0 + lc] : bias[lc];
        #pragma unroll
        for (int m = 0; m < 4; ++m) {
          int lr = m * 16 + rGrp;
          #pragma unroll
          for (int r = 0; r < 4; ++r) {
            float v = acc[m][n][r] + b;
            if (EPI == 0) v = (v >= 0.f) ? v : 0.01f * v;
            smem[(lr + r) * 128 + lc] = f2bf(v);
          }
        }
      }
    }
    __syncthreads();
    #pragma unroll
    for (int pass = 0; pass < 4; ++pass) {
      int chunk = pass * 256 + tid;
      int row = chunk >> 4, c8 = chunk & 15;
      int G = gr0 + s * 64 + row;
      if (G < M) {
        u16x8 v = *reinterpret_cast<const u16x8*>(smem + row * 128 + c8 * 8);
        if (EPI == 0)
          *reinterpret_cast<u16x8*>(outp + (size_t)G * 256 + gc0 + c8 * 8) = v;
        else
          *reinterpret_cast<u16x8*>(outp + (size_t)G * 128 + c8 * 8) = v;
      }
    }
    if (s == 0) __syncthreads();
  }
}

// ==================== launch ====================
extern "C" void kernel_launch(void* const* d_in, const int* in_sizes, int n_in,
                              void* d_out, int out_size, void* d_ws, size_t ws_size,
                              hipStream_t stream) {
  const float* emb_user    = (const float*)d_in[0];
  const float* emb_item    = (const float*)d_in[1];
  const float* W1_self_ui  = (const float*)d_in[2];
  const float* W1_neigh_ui = (const float*)d_in[3];
  const float* b1_ui       = (const float*)d_in[4];
  const float* W1_self_iu  = (const float*)d_in[5];
  const float* W1_neigh_iu = (const float*)d_in[6];
  const float* b1_iu       = (const float*)d_in[7];
  const float* W2_self_ui  = (const float*)d_in[8];
  const float* W2_neigh_ui = (const float*)d_in[9];
  const float* b2_ui       = (const float*)d_in[10];
  const float* W2_self_iu  = (const float*)d_in[11];
  const float* W2_neigh_iu = (const float*)d_in[12];
  const float* b2_iu       = (const float*)d_in[13];
  const int* e1_src = (const int*)d_in[14];
  const int* e1_dst = (const int*)d_in[15];
  const int* e2_src = (const int*)d_in[16];
  const int* e2_dst = (const int*)d_in[17];

  // ---- workspace ----
  u16* p16 = (u16*)d_ws;
  u16* ue     = p16; p16 += (size_t)NUc * 128;
  u16* ie     = p16; p16 += (size_t)NIc * 128;
  u16* h1i    = p16; p16 += (size_t)NIc * 256;
  u16* h1u    = p16; p16 += (size_t)NUc * 256;
  u16* aggb_i = p16; p16 += (size_t)NIc * 128;   // reused as proj_u2i after L1 GEMM
  u16* aggb_u = p16; p16 += (size_t)NUc * 128;   // reused as self_u after L1 GEMM
  u16* proj_i2u = p16; p16 += (size_t)NIc * 128;
  u16* self_i   = p16; p16 += (size_t)NIc * 128;
  u16* Wt1_ui  = p16; p16 += 256 * 256;
  u16* Wt1_iu  = p16; p16 += 256 * 256;
  u16* Wt2c_u  = p16; p16 += 256 * 256;
  u16* Wt2c_i  = p16; p16 += 256 * 256;
  u16* proj_u2i = aggb_i;   // alias (sequential reuse)
  u16* self_u   = aggb_u;   // alias
  int* ip    = (int*)p16;
  int* ideg1 = ip;  ip += NIc;
  int* ideg2 = ip;  ip += NUc;
  int* off1  = ip;  ip += NIc + 1;
  int* off2  = ip;  ip += NUc + 1;
  int* rank1 = ip;  ip += Ec;
  int* rank2 = ip;  ip += Ec;
  int* csr1  = ip;  ip += Ec;
  int* csr2  = ip;  ip += Ec;
  int* bsum1 = ip;  ip += 512;
  int* bscan1= ip;  ip += 512;
  int* bsum2 = ip;  ip += 512;
  int* bscan2= ip;  ip += 512;

  float* h2_user = (float*)d_out;
  float* h2_item = h2_user + (size_t)NUc * 128;

  dim3 blk(256);
  const int gather2Blocks = (200000 + 3) / 4;
  dim3 gemmGrid(782, 2, 2);

  // ---- prep: casts + weights, CSR ----
  hipMemsetAsync(ideg1, 0, sizeof(int) * (size_t)(NIc + NUc), stream);
  prep_all<<<4096, blk, 0, stream>>>(emb_user, emb_item,
                                     W1_self_ui, W1_neigh_ui, W1_self_iu, W1_neigh_iu,
                                     W2_self_ui, W2_neigh_ui, W2_self_iu, W2_neigh_iu,
                                     ue, ie, Wt1_ui, Wt1_iu, Wt2c_u, Wt2c_i);
  hist_kernel<<<1024, blk, 0, stream>>>(e1_dst, e2_dst, ideg1, ideg2, rank1, rank2);
  block_reduce2<<<dim3(NB, 2), blk, 0, stream>>>(ideg1, ideg2, bsum1, bsum2, NIc);
  scan_bsums2<<<2, 512, 0, stream>>>(bsum1, bsum2, bscan1, bscan2, NB);
  scan_blocks2<<<dim3(NB, 2), blk, 0, stream>>>(ideg1, ideg2, bscan1, bscan2, off1, off2, NIc);
  fill_csr_kernel<<<1024, blk, 0, stream>>>(e1_src, e1_dst, e2_src, e2_dst,
                                            rank1, rank2, off1, off2, csr1, csr2);

  // ---- layer 1: gather + fused GEMM -> h1 (bf16) ----
  gather2<<<gather2Blocks, blk, 0, stream>>>(ue, off1, csr1, aggb_i,
                                             ie, off2, csr2, aggb_u);
  mfma_gemm2<2, 0, 128><<<gemmGrid, blk, 0, stream>>>(
      ie, aggb_i, Wt1_ui, b1_ui, h1i, nullptr,
      ue, aggb_u, Wt1_iu, b1_iu, h1u, nullptr, Mrows);

  // ---- layer 2: combined dual-output GEMM (proj + self), h1 read once ----
  // z=0: A=h1u -> out0=proj_u2i (=h1u@W2n_ui), out1=self_u (=h1u@W2s_iu + b2_iu)
  // z=1: A=h1i -> out0=proj_i2u (=h1i@W2n_iu), out1=self_i (=h1i@W2s_ui + b2_ui)
  mfma_gemm2<1, 1, 256><<<gemmGrid, blk, 0, stream>>>(
      h1u, nullptr, Wt2c_u, b2_iu, proj_u2i, self_u,
      h1i, nullptr, Wt2c_i, b2_ui, proj_i2u, self_i, Mrows);

  // ---- layer 2: gather + final add -> f32 outputs ----
  gather_final<<<gather2Blocks, blk, 0, stream>>>(
      proj_u2i, off1, csr1, self_i, h2_item,
      proj_i2u, off2, csr2, self_u, h2_user);
}

// Round 6
// 365.398 us; speedup vs baseline: 11.4373x; 1.0682x over previous
//
#include <hip/hip_runtime.h>
#include <stdint.h>

typedef unsigned short u16;
typedef unsigned int   u32;
typedef __attribute__((ext_vector_type(8))) short bf16x8;
typedef __attribute__((ext_vector_type(4))) float f32x4;
typedef __attribute__((ext_vector_type(2))) float f32x2;
typedef __attribute__((ext_vector_type(8))) unsigned short u16x8;

constexpr int NUc = 100000;
constexpr int NIc = 100000;
constexpr int Ec  = 500000;
constexpr int Mrows = 100000;
constexpr int NB  = (100000 + 255) / 256;   // 391 scan blocks

__device__ __forceinline__ u16 f2bf(float f) {
  u32 u = __float_as_uint(f);
  u += 0x7fffu + ((u >> 16) & 1u);          // round-to-nearest-even
  return (u16)(u >> 16);
}
__device__ __forceinline__ float bf2f(u16 h) { return __uint_as_float(((u32)h) << 16); }

// ==================== fused cast + weight prep + degree histogram ====================
// blocks [0, PREP_B): cast/transpose (BW-bound streaming)
// blocks [PREP_B, PREP_B+HIST_B): degree histogram + rank (atomic-latency-bound)
constexpr int PREP_B = 4096;
constexpr int HIST_B = 1024;
__global__ void prep_hist(const float* __restrict__ eu, const float* __restrict__ ei,
                          const float* __restrict__ W1s_ui, const float* __restrict__ W1n_ui,
                          const float* __restrict__ W1s_iu, const float* __restrict__ W1n_iu,
                          const float* __restrict__ W2s_ui, const float* __restrict__ W2n_ui,
                          const float* __restrict__ W2s_iu, const float* __restrict__ W2n_iu,
                          u16* __restrict__ ue, u16* __restrict__ ie,
                          u16* __restrict__ Wt1_ui, u16* __restrict__ Wt1_iu,
                          u16* __restrict__ Wt2c_u, u16* __restrict__ Wt2c_i,
                          const int* __restrict__ e1_dst, const int* __restrict__ e2_dst,
                          int* __restrict__ ideg1, int* __restrict__ ideg2,
                          int* __restrict__ rank1, int* __restrict__ rank2) {
  if (blockIdx.x < PREP_B) {
    constexpr int N4 = NUc * 128 / 4;
    constexpr int TOT = 2 * N4 + 262144;
    int i = blockIdx.x * blockDim.x + threadIdx.x;
    const int stride = PREP_B * 256;
    for (int t = i; t < TOT; t += stride) {
      if (t < 2 * N4) {
        const float* src = (t < N4) ? eu : ei;
        u16* dst = (t < N4) ? ue : ie;
        int c = (t < N4) ? t : t - N4;
        f32x4 v = __builtin_nontemporal_load(reinterpret_cast<const f32x4*>(src) + c);
        ushort4 o;
        o.x = f2bf(v.x); o.y = f2bf(v.y); o.z = f2bf(v.z); o.w = f2bf(v.w);
        reinterpret_cast<ushort4*>(dst)[c] = o;   // cached: table re-read by gather2/gemm
      } else {
        int j = t - 2 * N4;
        if (j < 131072) {                      // Wt1
          const float* Ws = (j < 65536) ? W1s_ui : W1s_iu;
          const float* Wn = (j < 65536) ? W1n_ui : W1n_iu;
          u16* dst = (j < 65536) ? Wt1_ui : Wt1_iu;
          int q = j & 65535;
          int n = q >> 8, k = q & 255;
          dst[q] = f2bf(k < 128 ? Ws[k * 256 + n] : Wn[(k - 128) * 256 + n]);
        } else {                               // Wt2c
          int q = j - 131072;
          int which = q >> 16;                 // 0: A=h1u set, 1: A=h1i set
          int s = q & 65535;
          int c = s >> 8, k = s & 255;
          float v;
          if (which == 0) v = (c < 128) ? W2n_ui[k * 128 + c] : W2s_iu[k * 128 + (c - 128)];
          else            v = (c < 128) ? W2n_iu[k * 128 + c] : W2s_ui[k * 128 + (c - 128)];
          u16* dst = which ? Wt2c_i : Wt2c_u;
          dst[s] = f2bf(v);
        }
      }
    }
  } else {
    int i = (blockIdx.x - PREP_B) * blockDim.x + threadIdx.x;
    const int stride = HIST_B * 256;
    for (; i < 2 * Ec; i += stride) {
      if (i < Ec) rank1[i] = atomicAdd(&ideg1[e1_dst[i]], 1);
      else        rank2[i - Ec] = atomicAdd(&ideg2[e2_dst[i - Ec]], 1);
    }
  }
}

// ==================== CSR scans ====================
__global__ void block_reduce2(const int* __restrict__ ideg1, const int* __restrict__ ideg2,
                              int* __restrict__ bsum1, int* __restrict__ bsum2, int n) {
  const int* deg = blockIdx.y ? ideg2 : ideg1;
  int* bsum = blockIdx.y ? bsum2 : bsum1;
  __shared__ int s[256];
  int t = threadIdx.x, i = blockIdx.x * 256 + t;
  s[t] = (i < n) ? deg[i] : 0;
  __syncthreads();
  for (int st = 128; st > 0; st >>= 1) { if (t < st) s[t] += s[t + st]; __syncthreads(); }
  if (t == 0) bsum[blockIdx.x] = s[0];
}

__global__ void scan_bsums2(const int* __restrict__ bsum1, const int* __restrict__ bsum2,
                            int* __restrict__ bscan1, int* __restrict__ bscan2, int nb) {
  const int* bsum = blockIdx.x ? bsum2 : bsum1;
  int* bscan = blockIdx.x ? bscan2 : bscan1;
  __shared__ int s[512];
  int t = threadIdx.x;
  int v0 = (t < nb) ? bsum[t] : 0;
  s[t] = v0;
  __syncthreads();
  for (int d = 1; d < 512; d <<= 1) {
    int v = (t >= d) ? s[t - d] : 0;
    __syncthreads();
    s[t] += v;
    __syncthreads();
  }
  if (t < nb) bscan[t] = s[t] - v0;   // exclusive
}

__global__ void scan_blocks2(const int* __restrict__ ideg1, const int* __restrict__ ideg2,
                             const int* __restrict__ bscan1, const int* __restrict__ bscan2,
                             int* __restrict__ off1, int* __restrict__ off2, int n) {
  const int* deg = blockIdx.y ? ideg2 : ideg1;
  const int* bscan = blockIdx.y ? bscan2 : bscan1;
  int* off = blockIdx.y ? off2 : off1;
  __shared__ int s[256];
  int t = threadIdx.x, i = blockIdx.x * 256 + t;
  int d = (i < n) ? deg[i] : 0;
  s[t] = d;
  __syncthreads();
  for (int st = 1; st < 256; st <<= 1) {
    int v = (t >= st) ? s[t - st] : 0;
    __syncthreads();
    s[t] += v;
    __syncthreads();
  }
  if (i < n) off[i] = bscan[blockIdx.x] + s[t] - d;
  if (i == 0) off[n] = Ec;
}

__global__ void fill_csr_kernel(const int* __restrict__ e1_src, const int* __restrict__ e1_dst,
                                const int* __restrict__ e2_src, const int* __restrict__ e2_dst,
                                const int* __restrict__ rank1, const int* __restrict__ rank2,
                                const int* __restrict__ off1, const int* __restrict__ off2,
                                int* __restrict__ csr1, int* __restrict__ csr2) {
  int i = blockIdx.x * blockDim.x + threadIdx.x;
  const int stride = gridDim.x * blockDim.x;
  for (; i < 2 * Ec; i += stride) {
    if (i < Ec) {
      int d = __builtin_nontemporal_load(e1_dst + i);
      int r = __builtin_nontemporal_load(rank1 + i);
      csr1[off1[d] + r] = __builtin_nontemporal_load(e1_src + i);
    } else {
      int e = i - Ec;
      int d = __builtin_nontemporal_load(e2_dst + e);
      int r = __builtin_nontemporal_load(rank2 + e);
      csr2[off2[d] + r] = __builtin_nontemporal_load(e2_src + e);
    }
  }
}

// ==================== gather-mean x2 segments (bf16 -> bf16), one wave per dst row ====================
__global__ __launch_bounds__(256) void gather2(const u16* __restrict__ fA, const int* __restrict__ offA,
                                               const int* __restrict__ csrA, u16* __restrict__ outA,
                                               const u16* __restrict__ fB, const int* __restrict__ offB,
                                               const int* __restrict__ csrB, u16* __restrict__ outB) {
  const int wid  = (blockIdx.x * blockDim.x + threadIdx.x) >> 6;
  const int lane = threadIdx.x & 63;
  const u16* f; const int* off; const int* csr; u16* out; int r;
  if (wid < 100000)      { f = fA; off = offA; csr = csrA; out = outA; r = wid; }
  else if (wid < 200000) { f = fB; off = offB; csr = csrB; out = outB; r = wid - 100000; }
  else return;
  const int j0 = off[r], j1 = off[r + 1];
  const int colb = lane << 1;
  float ax = 0.f, ay = 0.f;
  for (int jb = j0; jb < j1; jb += 64) {
    int cnt = min(64, j1 - jb);
    int idx = (jb + lane < j1) ? csr[jb + lane] : 0;
    int t = 0;
    for (; t + 4 <= cnt; t += 4) {
      int s0 = __shfl(idx, t),     s1 = __shfl(idx, t + 1);
      int s2 = __shfl(idx, t + 2), s3 = __shfl(idx, t + 3);
      u32 v0 = *reinterpret_cast<const u32*>(f + (size_t)s0 * 128 + colb);
      u32 v1 = *reinterpret_cast<const u32*>(f + (size_t)s1 * 128 + colb);
      u32 v2 = *reinterpret_cast<const u32*>(f + (size_t)s2 * 128 + colb);
      u32 v3 = *reinterpret_cast<const u32*>(f + (size_t)s3 * 128 + colb);
      ax += __uint_as_float(v0 << 16) + __uint_as_float(v1 << 16)
          + __uint_as_float(v2 << 16) + __uint_as_float(v3 << 16);
      ay += __uint_as_float(v0 & 0xffff0000u) + __uint_as_float(v1 & 0xffff0000u)
          + __uint_as_float(v2 & 0xffff0000u) + __uint_as_float(v3 & 0xffff0000u);
    }
    for (; t < cnt; ++t) {
      int s0 = __shfl(idx, t);
      u32 v0 = *reinterpret_cast<const u32*>(f + (size_t)s0 * 128 + colb);
      ax += __uint_as_float(v0 << 16);
      ay += __uint_as_float(v0 & 0xffff0000u);
    }
  }
  float rs = 1.0f / fmaxf((float)(j1 - j0), 1.0f);
  u32 o = (u32)f2bf(ax * rs) | ((u32)f2bf(ay * rs) << 16);
  *reinterpret_cast<u32*>(out + (size_t)r * 128 + colb) = o;   // cached: re-read by gemmL1
}

// ==================== final gather: out_f32 = bf16(self) + mean(proj[csr]) ====================
__global__ __launch_bounds__(256) void gather_final(
    const u16* __restrict__ pA, const int* __restrict__ offA, const int* __restrict__ csrA,
    const u16* __restrict__ sA, float* __restrict__ oA,
    const u16* __restrict__ pB, const int* __restrict__ offB, const int* __restrict__ csrB,
    const u16* __restrict__ sB, float* __restrict__ oB) {
  const int wid  = (blockIdx.x * blockDim.x + threadIdx.x) >> 6;
  const int lane = threadIdx.x & 63;
  const u16* f; const int* off; const int* csr; const u16* sf; float* out; int r;
  if (wid < 100000)      { f = pA; off = offA; csr = csrA; sf = sA; out = oA; r = wid; }
  else if (wid < 200000) { f = pB; off = offB; csr = csrB; sf = sB; out = oB; r = wid - 100000; }
  else return;
  const int j0 = off[r], j1 = off[r + 1];
  const int colb = lane << 1;
  float ax = 0.f, ay = 0.f;
  for (int jb = j0; jb < j1; jb += 64) {
    int cnt = min(64, j1 - jb);
    int idx = (jb + lane < j1) ? csr[jb + lane] : 0;
    int t = 0;
    for (; t + 4 <= cnt; t += 4) {
      int s0 = __shfl(idx, t),     s1 = __shfl(idx, t + 1);
      int s2 = __shfl(idx, t + 2), s3 = __shfl(idx, t + 3);
      u32 v0 = *reinterpret_cast<const u32*>(f + (size_t)s0 * 128 + colb);
      u32 v1 = *reinterpret_cast<const u32*>(f + (size_t)s1 * 128 + colb);
      u32 v2 = *reinterpret_cast<const u32*>(f + (size_t)s2 * 128 + colb);
      u32 v3 = *reinterpret_cast<const u32*>(f + (size_t)s3 * 128 + colb);
      ax += __uint_as_float(v0 << 16) + __uint_as_float(v1 << 16)
          + __uint_as_float(v2 << 16) + __uint_as_float(v3 << 16);
      ay += __uint_as_float(v0 & 0xffff0000u) + __uint_as_float(v1 & 0xffff0000u)
          + __uint_as_float(v2 & 0xffff0000u) + __uint_as_float(v3 & 0xffff0000u);
    }
    for (; t < cnt; ++t) {
      int s0 = __shfl(idx, t);
      u32 v0 = *reinterpret_cast<const u32*>(f + (size_t)s0 * 128 + colb);
      ax += __uint_as_float(v0 << 16);
      ay += __uint_as_float(v0 & 0xffff0000u);
    }
  }
  float rs = 1.0f / fmaxf((float)(j1 - j0), 1.0f);
  u32 sv = __builtin_nontemporal_load(reinterpret_cast<const u32*>(sf + (size_t)r * 128 + colb));
  f32x2 o;
  o.x = ax * rs + __uint_as_float(sv << 16);
  o.y = ay * rs + __uint_as_float(sv & 0xffff0000u);
  __builtin_nontemporal_store(o, reinterpret_cast<f32x2*>(out + (size_t)r * 128 + colb));
}

// ==================== MFMA GEMM, z-batched, LDS-coalesced epilogue ====================
// EPI 0: h1 = leaky([X;S]@W1 + b1), single bf16 out (ldout 256), grid.y = col-tile
// EPI 1: dual out (ldout 128): y=0 -> out0 = A@Wn (no bias); y=1 -> out1 = A@Ws + bias (nt-store)
__device__ __forceinline__ void glds16(const void* g, void* l) {
  __builtin_amdgcn_global_load_lds((const __attribute__((address_space(1))) void*)g,
                                   (__attribute__((address_space(3))) void*)l, 16, 0, 0);
}

template<int NTAB, int EPI, int AST>
__global__ __launch_bounds__(256) void mfma_gemm2(
    const u16* __restrict__ A0a, const u16* __restrict__ A1a, const u16* __restrict__ Bta,
    const float* __restrict__ biasa, u16* __restrict__ out0a, u16* __restrict__ out1a,
    const u16* __restrict__ A0b, const u16* __restrict__ A1b, const u16* __restrict__ Btb,
    const float* __restrict__ biasb, u16* __restrict__ out0b, u16* __restrict__ out1b,
    int M)
{
  constexpr int K = 256, BK = 32, BM = 128;
  __shared__ __align__(16) u16 smem[8192];   // As: [0,4096) Bs: [4096,8192); epilogue slab: all 16KB
  u16* As = smem;
  u16* Bs = smem + 4096;

  const bool zb = (blockIdx.z != 0);
  const u16* A0 = zb ? A0b : A0a;
  const u16* A1 = zb ? A1b : A1a;
  const u16* Bt = zb ? Btb : Bta;
  const float* bias = zb ? biasb : biasa;

  const int tid  = threadIdx.x;
  const int lane = tid & 63;
  const int w    = tid >> 6;
  const int wr   = w >> 1, wc = w & 1;
  const int gr0  = blockIdx.x * BM;
  const int gc0  = blockIdx.y * BM;

  f32x4 acc[4][4];
  #pragma unroll
  for (int m = 0; m < 4; ++m)
    #pragma unroll
    for (int n = 0; n < 4; ++n) acc[m][n] = (f32x4){0.f, 0.f, 0.f, 0.f};

  const int srow  = lane >> 2;   // 0..15 within a 16-row chunk
  const int sslot = lane & 3;    // 16B slot within 64B row

  for (int kt = 0; kt < K; kt += BK) {
    const u16* At = (NTAB == 2 && kt >= 128) ? A1 : A0;
    const int kbase = (NTAB == 2) ? (kt & 127) : kt;
    #pragma unroll
    for (int c = 0; c < 2; ++c) {
      int rl = w * 32 + c * 16 + srow;                 // LDS-local row 0..127
      int swz = (sslot ^ ((rl >> 1) & 3)) << 3;        // swizzled k-slot (elements)
      int grow = gr0 + rl; grow = grow < M ? grow : M - 1;
      glds16(At + (size_t)grow * AST + kbase + swz, As + (size_t)(w * 32 + c * 16) * BK);
      glds16(Bt + (size_t)(gc0 + rl) * K + kt + swz, Bs + (size_t)(w * 32 + c * 16) * BK);
    }
    __syncthreads();

    bf16x8 af[4], bfr[4];
    #pragma unroll
    for (int m = 0; m < 4; ++m) {
      int row = wr * 64 + m * 16 + (lane & 15);
      int idx = (row << 5) + ((((lane >> 4) ^ ((row >> 1) & 3))) << 3);
      af[m] = *reinterpret_cast<const bf16x8*>(As + idx);
    }
    #pragma unroll
    for (int n = 0; n < 4; ++n) {
      int row = wc * 64 + n * 16 + (lane & 15);
      int idx = (row << 5) + ((((lane >> 4) ^ ((row >> 1) & 3))) << 3);
      bfr[n] = *reinterpret_cast<const bf16x8*>(Bs + idx);
    }
    #pragma unroll
    for (int m = 0; m < 4; ++m)
      #pragma unroll
      for (int n = 0; n < 4; ++n)
        acc[m][n] = __builtin_amdgcn_mfma_f32_16x16x32_bf16(af[m], bfr[n], acc[m][n], 0, 0, 0);
    __syncthreads();
  }

  // ---- epilogue: acc -> LDS slab (64 rows x 128 cols bf16) -> coalesced 16B stores ----
  u16* outp;
  if (EPI == 0) outp = zb ? out0b : out0a;
  else          outp = (blockIdx.y == 0) ? (zb ? out0b : out0a) : (zb ? out1b : out1a);
  const bool useBias = (EPI == 0) || (blockIdx.y == 1);
  const bool ntStore = (EPI == 1) && (blockIdx.y == 1);   // self_* : read once, streaming

  const int cLane = lane & 15;
  const int rGrp  = (lane >> 4) << 2;
  for (int s = 0; s < 2; ++s) {
    if (wr == s) {
      #pragma unroll
      for (int n = 0; n < 4; ++n) {
        int lc = wc * 64 + n * 16 + cLane;             // 0..127 local col
        float b = 0.f;
        if (useBias) b = (EPI == 0) ? bias[gc0 + lc] : bias[lc];
        #pragma unroll
        for (int m = 0; m < 4; ++m) {
          int lr = m * 16 + rGrp;
          #pragma unroll
          for (int r = 0; r < 4; ++r) {
            float v = acc[m][n][r] + b;
            if (EPI == 0) v = (v >= 0.f) ? v : 0.01f * v;
            smem[(lr + r) * 128 + lc] = f2bf(v);
          }
        }
      }
    }
    __syncthreads();
    #pragma unroll
    for (int pass = 0; pass < 4; ++pass) {
      int chunk = pass * 256 + tid;
      int row = chunk >> 4, c8 = chunk & 15;
      int G = gr0 + s * 64 + row;
      if (G < M) {
        u16x8 v = *reinterpret_cast<const u16x8*>(smem + row * 128 + c8 * 8);
        if (EPI == 0)
          *reinterpret_cast<u16x8*>(outp + (size_t)G * 256 + gc0 + c8 * 8) = v;
        else if (ntStore)
          __builtin_nontemporal_store(v, reinterpret_cast<u16x8*>(outp + (size_t)G * 128 + c8 * 8));
        else
          *reinterpret_cast<u16x8*>(outp + (size_t)G * 128 + c8 * 8) = v;
      }
    }
    if (s == 0) __syncthreads();
  }
}

// ==================== launch ====================
extern "C" void kernel_launch(void* const* d_in, const int* in_sizes, int n_in,
                              void* d_out, int out_size, void* d_ws, size_t ws_size,
                              hipStream_t stream) {
  const float* emb_user    = (const float*)d_in[0];
  const float* emb_item    = (const float*)d_in[1];
  const float* W1_self_ui  = (const float*)d_in[2];
  const float* W1_neigh_ui = (const float*)d_in[3];
  const float* b1_ui       = (const float*)d_in[4];
  const float* W1_self_iu  = (const float*)d_in[5];
  const float* W1_neigh_iu = (const float*)d_in[6];
  const float* b1_iu       = (const float*)d_in[7];
  const float* W2_self_ui  = (const float*)d_in[8];
  const float* W2_neigh_ui = (const float*)d_in[9];
  const float* b2_ui       = (const float*)d_in[10];
  const float* W2_self_iu  = (const float*)d_in[11];
  const float* W2_neigh_iu = (const float*)d_in[12];
  const float* b2_iu       = (const float*)d_in[13];
  const int* e1_src = (const int*)d_in[14];
  const int* e1_dst = (const int*)d_in[15];
  const int* e2_src = (const int*)d_in[16];
  const int* e2_dst = (const int*)d_in[17];

  // ---- workspace ----
  u16* p16 = (u16*)d_ws;
  u16* ue     = p16; p16 += (size_t)NUc * 128;
  u16* ie     = p16; p16 += (size_t)NIc * 128;
  u16* h1i    = p16; p16 += (size_t)NIc * 256;
  u16* h1u    = p16; p16 += (size_t)NUc * 256;
  u16* aggb_i = p16; p16 += (size_t)NIc * 128;   // reused as proj_u2i after L1 GEMM
  u16* aggb_u = p16; p16 += (size_t)NUc * 128;   // reused as self_u after L1 GEMM
  u16* proj_i2u = p16; p16 += (size_t)NIc * 128;
  u16* self_i   = p16; p16 += (size_t)NIc * 128;
  u16* Wt1_ui  = p16; p16 += 256 * 256;
  u16* Wt1_iu  = p16; p16 += 256 * 256;
  u16* Wt2c_u  = p16; p16 += 256 * 256;
  u16* Wt2c_i  = p16; p16 += 256 * 256;
  u16* proj_u2i = aggb_i;   // alias (sequential reuse)
  u16* self_u   = aggb_u;   // alias
  int* ip    = (int*)p16;
  int* ideg1 = ip;  ip += NIc;
  int* ideg2 = ip;  ip += NUc;
  int* off1  = ip;  ip += NIc + 1;
  int* off2  = ip;  ip += NUc + 1;
  int* rank1 = ip;  ip += Ec;
  int* rank2 = ip;  ip += Ec;
  int* csr1  = ip;  ip += Ec;
  int* csr2  = ip;  ip += Ec;
  int* bsum1 = ip;  ip += 512;
  int* bscan1= ip;  ip += 512;
  int* bsum2 = ip;  ip += 512;
  int* bscan2= ip;  ip += 512;

  float* h2_user = (float*)d_out;
  float* h2_item = h2_user + (size_t)NUc * 128;

  dim3 blk(256);
  const int gather2Blocks = (200000 + 3) / 4;
  dim3 gemmGrid(782, 2, 2);

  // ---- prep (casts + weights) overlapped with degree histogram ----
  hipMemsetAsync(ideg1, 0, sizeof(int) * (size_t)(NIc + NUc), stream);
  prep_hist<<<PREP_B + HIST_B, blk, 0, stream>>>(
      emb_user, emb_item,
      W1_self_ui, W1_neigh_ui, W1_self_iu, W1_neigh_iu,
      W2_self_ui, W2_neigh_ui, W2_self_iu, W2_neigh_iu,
      ue, ie, Wt1_ui, Wt1_iu, Wt2c_u, Wt2c_i,
      e1_dst, e2_dst, ideg1, ideg2, rank1, rank2);
  block_reduce2<<<dim3(NB, 2), blk, 0, stream>>>(ideg1, ideg2, bsum1, bsum2, NIc);
  scan_bsums2<<<2, 512, 0, stream>>>(bsum1, bsum2, bscan1, bscan2, NB);
  scan_blocks2<<<dim3(NB, 2), blk, 0, stream>>>(ideg1, ideg2, bscan1, bscan2, off1, off2, NIc);
  fill_csr_kernel<<<1024, blk, 0, stream>>>(e1_src, e1_dst, e2_src, e2_dst,
                                            rank1, rank2, off1, off2, csr1, csr2);

  // ---- layer 1: gather + fused GEMM -> h1 (bf16) ----
  gather2<<<gather2Blocks, blk, 0, stream>>>(ue, off1, csr1, aggb_i,
                                             ie, off2, csr2, aggb_u);
  mfma_gemm2<2, 0, 128><<<gemmGrid, blk, 0, stream>>>(
      ie, aggb_i, Wt1_ui, b1_ui, h1i, nullptr,
      ue, aggb_u, Wt1_iu, b1_iu, h1u, nullptr, Mrows);

  // ---- layer 2: combined dual-output GEMM (proj + self), h1 read once ----
  mfma_gemm2<1, 1, 256><<<gemmGrid, blk, 0, stream>>>(
      h1u, nullptr, Wt2c_u, b2_iu, proj_u2i, self_u,
      h1i, nullptr, Wt2c_i, b2_ui, proj_i2u, self_i, Mrows);

  // ---- layer 2: gather + final add -> f32 outputs ----
  gather_final<<<gather2Blocks, blk, 0, stream>>>(
      proj_u2i, off1, csr1, self_i, h2_item,
      proj_i2u, off2, csr2, self_u, h2_user);
}